// Round 11
// baseline (530.993 us; speedup 1.0000x reference)
//
#include <hip/hip_runtime.h>
#include <stdint.h>
#include <stddef.h>

// Shapes: D=512, F=2048, H=8, L=128, B=4
#define NTOK 512      // B*L tokens
#define NM   65536    // B*L*L edge rows

typedef __bf16 bf16x8 __attribute__((ext_vector_type(8)));
typedef float  f32x4  __attribute__((ext_vector_type(4)));
typedef unsigned int u32x4 __attribute__((ext_vector_type(4)));

__device__ __forceinline__ unsigned short f2bf(float f) {
    unsigned int u = __builtin_bit_cast(unsigned int, f);
    u += 0x7FFFu + ((u >> 16) & 1u);
    return (unsigned short)(u >> 16);
}
__device__ __forceinline__ float bf2f(unsigned short s) {
    unsigned int u = ((unsigned int)s) << 16;
    return __builtin_bit_cast(float, u);
}

// async global->LDS, 16B per lane; LDS dest is wave-uniform base + lane*16
__device__ __forceinline__ void gload16(const void* g, void* l) {
    __builtin_amdgcn_global_load_lds(
        (const __attribute__((address_space(1))) void*)g,
        (__attribute__((address_space(3))) void*)l,
        16, 0, 0);
}

// ---------- merged prep: h-transpose + k_w transpose + concat bias ----------
__global__ __launch_bounds__(256) void k_prep(const float* __restrict__ h,
                                              unsigned short* __restrict__ Qm,
                                              const float* __restrict__ kw,
                                              float* __restrict__ kwT,
                                              const float* __restrict__ Wob,
                                              const float* __restrict__ Wib,
                                              const float* __restrict__ qb,
                                              float* __restrict__ bias1) {
    int bid = blockIdx.x;
    int t = threadIdx.x;
    if (bid < 1024) {                       // h (L,B,D) -> Qm bf16 (b*128+i, 512)
        int idx = bid * 256 + t;
        int tok = idx >> 9, d = idx & 511;
        int b = tok >> 7, i = tok & 127;
        Qm[idx] = f2bf(h[(i * 4 + b) * 512 + d]);
    } else if (bid < 2048) {                // kwT[e][d] = k_w[d][e]
        int idx = (bid - 1024) * 256 + t;
        kwT[idx] = kw[(size_t)(idx & 511) * 512 + (idx >> 9)];
    } else {                                // bias1 concat
        int i = (bid - 2048) * 256 + t;
        if (i < 2560) {
            float v = 0.f;
            if (i < 512) v = Wob[i];
            else if (i < 1024) v = 0.f;
            else if (i < 1536) v = Wib[i - 1024];
            else if (i < 2048) v = 0.f;
            else v = qb[i - 2048] * 0.125f;
            bias1[i] = v;
        }
    }
}

// ---------- merged LDS-tiled fp32 -> bf16 transposes (job table) ----------
struct TRJob { const float* src; unsigned short* dst; int srcLd, dstLd, tcols; float scale; };
struct TRJobs { TRJob j[11]; int start[12]; };

__global__ __launch_bounds__(256) void k_trN(TRJobs js) {
    __shared__ float tile[64][65];
    int b = blockIdx.x;
    int ji = 0;
    while (ji < 10 && b >= js.start[ji + 1]) ++ji;
    TRJob jb = js.j[ji];
    int rel = b - js.start[ji];
    int bx = rel % jb.tcols, by = rel / jb.tcols;
    int r0 = by * 64, c0 = bx * 64;
    int t = threadIdx.x;
    int c = t & 63, rr = t >> 6;                // rr in 0..3
    #pragma unroll
    for (int ii = 0; ii < 16; ++ii) {
        int r = ii * 4 + rr;
        tile[r][c] = jb.src[(size_t)(r0 + r) * jb.srcLd + c0 + c];
    }
    __syncthreads();
    #pragma unroll
    for (int ii = 0; ii < 16; ++ii) {
        int n = ii * 4 + rr;                    // local col of src = row of dst
        jb.dst[(size_t)(c0 + n) * jb.dstLd + r0 + c] = f2bf(tile[c][n] * jb.scale);
    }
}

// ---------- generic bf16 MFMA GEMM: out = relu(A@B^T + bias*biasScale) [+accs] ----------
struct MMP {
    const unsigned short* A;  int lda;
    const unsigned short* Bt; int ldb;
    const float* bias;
    const float* accs;
    float* outF;
    unsigned short* outB;
    int ldo;
    int K;
    int relu;
    int aOffPerN64;
    int zKOff;
    int zOutOff;
    float biasScale;
};

__global__ __launch_bounds__(256) void k_mm(MMP p) {
    __shared__ unsigned char As[64 * 128];
    __shared__ unsigned char Bs[64 * 128];
    int t = threadIdx.x;
    int lane = t & 63, w = t >> 6;
    int m0 = blockIdx.x * 64, n0 = blockIdx.y * 64;
    int z = blockIdx.z;
    const unsigned short* A  = p.A + (size_t)(n0 >> 6) * p.aOffPerN64 + (size_t)z * p.zKOff;
    const unsigned short* Bt = p.Bt + (size_t)z * p.zKOff;
    int wm = (w >> 1) * 32, wn = (w & 1) * 32;
    f32x4 acc[2][2];
    #pragma unroll
    for (int a = 0; a < 2; ++a)
        #pragma unroll
        for (int b = 0; b < 2; ++b) acc[a][b] = (f32x4){0.f, 0.f, 0.f, 0.f};

    for (int kb = 0; kb < p.K; kb += 64) {
        __syncthreads();
        #pragma unroll
        for (int s = 0; s < 2; ++s) {
            int c = t + s * 256;
            int r = c >> 3, kc = (c & 7) * 8;
            int off = (r * 128 + kc * 2) ^ ((r & 7) << 4);
            *reinterpret_cast<u32x4*>(As + off) =
                *reinterpret_cast<const u32x4*>(A + (size_t)(m0 + r) * p.lda + kb + kc);
            *reinterpret_cast<u32x4*>(Bs + off) =
                *reinterpret_cast<const u32x4*>(Bt + (size_t)(n0 + r) * p.ldb + kb + kc);
        }
        __syncthreads();
        #pragma unroll
        for (int kh = 0; kh < 2; ++kh) {
            int kk = kh * 32 + (lane >> 4) * 8;
            bf16x8 af[2], bfr[2];
            #pragma unroll
            for (int mf = 0; mf < 2; ++mf) {
                int r = wm + mf * 16 + (lane & 15);
                int off = (r * 128 + kk * 2) ^ ((r & 7) << 4);
                af[mf] = *reinterpret_cast<const bf16x8*>(As + off);
            }
            #pragma unroll
            for (int nf = 0; nf < 2; ++nf) {
                int r = wn + nf * 16 + (lane & 15);
                int off = (r * 128 + kk * 2) ^ ((r & 7) << 4);
                bfr[nf] = *reinterpret_cast<const bf16x8*>(Bs + off);
            }
            #pragma unroll
            for (int mf = 0; mf < 2; ++mf)
                #pragma unroll
                for (int nf = 0; nf < 2; ++nf)
                    acc[mf][nf] = __builtin_amdgcn_mfma_f32_16x16x32_bf16(
                        af[mf], bfr[nf], acc[mf][nf], 0, 0, 0);
        }
    }
    #pragma unroll
    for (int mf = 0; mf < 2; ++mf) {
        #pragma unroll
        for (int rr = 0; rr < 4; ++rr) {
            int gm = m0 + wm + mf * 16 + (lane >> 4) * 4 + rr;
            #pragma unroll
            for (int nf = 0; nf < 2; ++nf) {
                int e = n0 + wn + nf * 16 + (lane & 15);
                float v = acc[mf][nf][rr];
                if (p.bias) v += p.bias[e] * p.biasScale;
                if (p.relu) v = fmaxf(v, 0.f);
                if (p.accs) v += p.accs[(size_t)gm * p.ldo + e];
                size_t oo = (size_t)gm * p.ldo + e + (size_t)z * p.zOutOff;
                if (p.outF) p.outF[oo] = v;
                if (p.outB) p.outB[oo] = f2bf(v);
            }
        }
    }
}

// ---------- p[tok][h][d] = sum_dh kwT[h*64+dh][d]*qs[tok][h*64+dh]; c[tok][h] ----------
__global__ __launch_bounds__(256) void k_prep2(const float* __restrict__ qs, int qld,
                                               const float* __restrict__ kwT,
                                               const float* __restrict__ k_b,
                                               unsigned short* __restrict__ p,
                                               float* __restrict__ c) {
    __shared__ float q8[8][512];
    int t = threadIdx.x;
    int tok0 = blockIdx.x * 8;
    int d = blockIdx.y * 256 + t;
    for (int idx = t; idx < 4096; idx += 256) {
        int s = idx >> 9, dd = idx & 511;
        q8[s][dd] = qs[(size_t)(tok0 + s) * qld + dd];
    }
    __syncthreads();
    if (blockIdx.y == 0 && t < 64) {
        int s = t >> 3, hh = t & 7;
        float cv = 0.f;
        for (int dh = 0; dh < 64; ++dh) cv += k_b[hh * 64 + dh] * q8[s][hh * 64 + dh];
        c[(tok0 + s) * 8 + hh] = cv;
    }
    for (int hh = 0; hh < 8; ++hh) {
        float pv[8];
        #pragma unroll
        for (int s = 0; s < 8; ++s) pv[s] = 0.f;
        for (int dh = 0; dh < 64; ++dh) {
            float wv = kwT[(size_t)(hh * 64 + dh) * 512 + d];
            #pragma unroll
            for (int s = 0; s < 8; ++s) pv[s] += wv * q8[s][hh * 64 + dh];
        }
        #pragma unroll
        for (int s = 0; s < 8; ++s)
            p[((size_t)(tok0 + s) * 8 + hh) * 512 + d] = f2bf(pv[s]);
    }
}

// ---------- edge MLP: U = relu(fixed[tokI] + arc@W2 + row[tokJ]) -> bf16 ----------
// A-direct: each wave loads its own A fragments global->VGPR->cvt->MFMA (no
// barrier coupling; siblings share the A slab via L2). B (W2t, L2-resident)
// is the only LDS-staged operand: 2x16KB double-buffer, B(t+1) issued right
// after the single per-step barrier so its latency hides under compute.
__global__ __launch_bounds__(256) void k_midU(const float* __restrict__ arc,
                                              const unsigned short* __restrict__ W2t,
                                              const float* __restrict__ fixedMat, int fld,
                                              const float* __restrict__ rowMat, int rld,
                                              unsigned short* __restrict__ U) {
    __shared__ unsigned short Bs2[2][128 * 64];   // 2 x 16KB bf16 B
    int t = threadIdx.x;
    int lane = t & 63;
    int w = t >> 6;
    int bid = blockIdx.x;
    int xcd = bid & 7, slot = bid >> 3;          // round-robin XCD dispatch
    int mt = xcd * 64 + (slot >> 2);             // 0..511 m-tile
    int nt = slot & 3;                           // 4 n-siblings adjacent on one XCD
    int m0 = mt * 128, n0 = nt * 128;
    int wm = (w >> 1) * 64, wn = (w & 1) * 64;
    f32x4 acc[4][4];
    #pragma unroll
    for (int a = 0; a < 4; ++a)
        #pragma unroll
        for (int bq = 0; bq < 4; ++bq) acc[a][bq] = (f32x4){0.f, 0.f, 0.f, 0.f};

    // B staging geometry: 4 issues/wave, 1KB each (8 rows x 128B)
    int brB = lane >> 3;                 // row within 8-row group
    int bcb = lane & 7;                  // 16B chunk within 128B row

    // A row pointers for this wave's fragment rows (per-lane)
    const float* aRow[4];
    #pragma unroll
    for (int mf = 0; mf < 4; ++mf)
        aRow[mf] = arc + (size_t)(m0 + wm + mf * 16 + (lane & 15)) * 512;

#define ISSUEB(KB, BUF)                                                         \
    _Pragma("unroll")                                                           \
    for (int i = 0; i < 4; ++i) {                                               \
        int base = (w * 4 + i) * 1024;                                          \
        int r = ((w * 4 + i) << 3) + brB;                                       \
        int cs = bcb ^ (r & 7);                                                 \
        gload16(W2t + (size_t)(n0 + r) * 512 + (KB) + cs * 8,                   \
                (char*)Bs2[BUF] + base);                                        \
    }

    ISSUEB(0, 0);
    #pragma unroll
    for (int kb8 = 0; kb8 < 8; ++kb8) {
        int kb = kb8 * 64;
        __syncthreads();                 // B(kb8) landed; prior buf reads done
        if (kb8 < 7) { ISSUEB(kb + 64, (kb8 & 1) ^ 1); }  // hides under compute
        #pragma unroll
        for (int kh = 0; kh < 2; ++kh) {
            int kk = kh * 32 + (lane >> 4) * 8;
            bf16x8 af[4], bfr[4];
            #pragma unroll
            for (int mf = 0; mf < 4; ++mf) {
                float4 a0 = *reinterpret_cast<const float4*>(aRow[mf] + kb + kk);
                float4 a1 = *reinterpret_cast<const float4*>(aRow[mf] + kb + kk + 4);
                af[mf][0] = (__bf16)a0.x; af[mf][1] = (__bf16)a0.y;
                af[mf][2] = (__bf16)a0.z; af[mf][3] = (__bf16)a0.w;
                af[mf][4] = (__bf16)a1.x; af[mf][5] = (__bf16)a1.y;
                af[mf][6] = (__bf16)a1.z; af[mf][7] = (__bf16)a1.w;
            }
            #pragma unroll
            for (int nf = 0; nf < 4; ++nf) {
                int rn = wn + nf * 16 + (lane & 15);
                int c = kk >> 3;
                bfr[nf] = *reinterpret_cast<const bf16x8*>(
                    (const char*)Bs2[kb8 & 1] + rn * 128 + ((c ^ (rn & 7)) << 4));
            }
            #pragma unroll
            for (int mf = 0; mf < 4; ++mf)
                #pragma unroll
                for (int nf = 0; nf < 4; ++nf)
                    acc[mf][nf] = __builtin_amdgcn_mfma_f32_16x16x32_bf16(
                        af[mf], bfr[nf], acc[mf][nf], 0, 0, 0);
        }
    }
#undef ISSUEB
    int tokI = mt;
    int bb = mt >> 7;
    float fx[4];
    #pragma unroll
    for (int nf = 0; nf < 4; ++nf)
        fx[nf] = fixedMat[(size_t)tokI * fld + n0 + wn + nf * 16 + (lane & 15)];
    #pragma unroll
    for (int mf = 0; mf < 4; ++mf) {
        #pragma unroll
        for (int r = 0; r < 4; ++r) {
            int row = wm + mf * 16 + (lane >> 4) * 4 + r;
            int gm = m0 + row;
            int tokJ = bb * 128 + (gm & 127);
            const float* rv = rowMat + (size_t)tokJ * rld;
            #pragma unroll
            for (int nf = 0; nf < 4; ++nf) {
                int e = n0 + wn + nf * 16 + (lane & 15);
                float v = acc[mf][nf][r] + fx[nf] + rv[e];
                v = fmaxf(v, 0.f);
                U[(size_t)gm * 512 + e] = f2bf(v);
            }
        }
    }
}

// ---------- fused scores+softmax+wacc (attn kept in 4KB LDS) ----------
// accum=0: Wsum (fp32) = attn@U ; accum=1: Waccb (bf16) = Wsum + attn@U
__global__ __launch_bounds__(256) void k_att2(const unsigned short* __restrict__ U,
                                              const unsigned short* __restrict__ p,
                                              const float* __restrict__ c,
                                              float* __restrict__ Wsum,
                                              unsigned short* __restrict__ Waccb,
                                              int accum) {
    __shared__ float at[8][128];
    int tok = blockIdx.x;
    int t = threadIdx.x;
    int w = t >> 6;
    int lane = t & 63;
    int hh = lane & 15;
    int kg = lane >> 4;
    bool hv = hh < 8;
    f32x4 acc[2];
    acc[0] = (f32x4){0.f, 0.f, 0.f, 0.f};
    acc[1] = (f32x4){0.f, 0.f, 0.f, 0.f};
    const unsigned short* Ub0 = U + (size_t)tok * 65536;
    const unsigned short* Ub = Ub0 + (size_t)(w * 32) * 512;
    const unsigned short* pb = p + ((size_t)tok * 8 + (hh & 7)) * 512;
    for (int ks = 0; ks < 16; ++ks) {
        int kcol = ks * 32 + kg * 8;
        u32x4 braw = (u32x4){0u, 0u, 0u, 0u};
        if (hv) braw = *reinterpret_cast<const u32x4*>(pb + kcol);
        bf16x8 bfrag = __builtin_bit_cast(bf16x8, braw);
        #pragma unroll
        for (int mf = 0; mf < 2; ++mf) {
            bf16x8 afrag = *reinterpret_cast<const bf16x8*>(
                Ub + (size_t)(mf * 16 + hh) * 512 + kcol);
            acc[mf] = __builtin_amdgcn_mfma_f32_16x16x32_bf16(afrag, bfrag, acc[mf], 0, 0, 0);
        }
    }
    if (hv) {
        float cval = c[tok * 8 + hh];
        #pragma unroll
        for (int mf = 0; mf < 2; ++mf)
            #pragma unroll
            for (int r = 0; r < 4; ++r)
                at[hh][w * 32 + mf * 16 + kg * 4 + r] = acc[mf][r] + cval;
    }
    __syncthreads();
    // softmax in place over j per head (8 groups x 32 lanes)
    {
        int h2 = t >> 5, l32 = t & 31;
        float v0 = at[h2][l32], v1 = at[h2][l32 + 32],
              v2 = at[h2][l32 + 64], v3 = at[h2][l32 + 96];
        float mx = fmaxf(fmaxf(v0, v1), fmaxf(v2, v3));
        #pragma unroll
        for (int o = 16; o >= 1; o >>= 1) mx = fmaxf(mx, __shfl_xor(mx, o));
        float e0 = __expf(v0 - mx), e1 = __expf(v1 - mx),
              e2 = __expf(v2 - mx), e3 = __expf(v3 - mx);
        float sum = e0 + e1 + e2 + e3;
        #pragma unroll
        for (int o = 16; o >= 1; o >>= 1) sum += __shfl_xor(sum, o);
        float inv = 1.f / sum;
        at[h2][l32]      = e0 * inv;
        at[h2][l32 + 32] = e1 * inv;
        at[h2][l32 + 64] = e2 * inv;
        at[h2][l32 + 96] = e3 * inv;
    }
    __syncthreads();
    // wacc: thread t covers d0=2t, all 8 heads; U re-read (L2/L3-hot)
    int d0 = t * 2;
    float a8[8][2];
    #pragma unroll
    for (int q = 0; q < 8; ++q) { a8[q][0] = 0.f; a8[q][1] = 0.f; }
    for (int j = 0; j < 128; ++j) {
        unsigned int uv = *reinterpret_cast<const unsigned int*>(Ub0 + (size_t)j * 512 + d0);
        float u0 = bf2f((unsigned short)(uv & 0xffffu));
        float u1 = bf2f((unsigned short)(uv >> 16));
        #pragma unroll
        for (int q = 0; q < 8; ++q) {
            float a = at[q][j];
            a8[q][0] += a * u0;
            a8[q][1] += a * u1;
        }
    }
    #pragma unroll
    for (int q = 0; q < 8; ++q) {
        size_t woff = ((size_t)tok * 8 + q) * 512 + d0;
        if (!accum) {
            Wsum[woff] = a8[q][0];
            Wsum[woff + 1] = a8[q][1];
        } else {
            float s0 = Wsum[woff] + a8[q][0];
            float s1 = Wsum[woff + 1] + a8[q][1];
            Waccb[woff] = f2bf(s0);
            Waccb[woff + 1] = f2bf(s1);
        }
    }
}

// ---------- layernorm: out = LN(A + B) * g + beta ----------
__global__ __launch_bounds__(256) void k_ln(const float* __restrict__ A,
                                            const float* __restrict__ Bv, int bswap,
                                            const float* __restrict__ parts,
                                            const float* __restrict__ pbias,
                                            const float* __restrict__ g,
                                            const float* __restrict__ bta,
                                            float* __restrict__ outF,
                                            unsigned short* __restrict__ outB) {
    int t = threadIdx.x;
    int tok = blockIdx.x;
    size_t aoff = (size_t)tok * 512;
    float b0, b1;
    if (parts) {
        b0 = parts[aoff + t] + parts[262144 + aoff + t] +
             parts[524288 + aoff + t] + parts[786432 + aoff + t] + pbias[t];
        b1 = parts[aoff + t + 256] + parts[262144 + aoff + t + 256] +
             parts[524288 + aoff + t + 256] + parts[786432 + aoff + t + 256] + pbias[t + 256];
    } else {
        size_t boff = aoff;
        if (bswap) { int i = tok >> 2, b = tok & 3; boff = (size_t)(b * 128 + i) * 512; }
        b0 = Bv[boff + t];
        b1 = Bv[boff + t + 256];
    }
    float v0 = A[aoff + t] + b0;
    float v1 = A[aoff + t + 256] + b1;
    float s = v0 + v1, q = v0 * v0 + v1 * v1;
    #pragma unroll
    for (int o = 32; o >= 1; o >>= 1) { s += __shfl_xor(s, o); q += __shfl_xor(q, o); }
    __shared__ float red[8];
    int w = t >> 6, lane = t & 63;
    if (lane == 0) { red[w] = s; red[4 + w] = q; }
    __syncthreads();
    float ts = red[0] + red[1] + red[2] + red[3];
    float tq = red[4] + red[5] + red[6] + red[7];
    float mean = ts * (1.f / 512.f);
    float var = tq * (1.f / 512.f) - mean * mean;
    float inv = rsqrtf(var + 1e-5f);
    float o0 = (v0 - mean) * inv * g[t] + bta[t];
    float o1 = (v1 - mean) * inv * g[t + 256] + bta[t + 256];
    outF[aoff + t] = o0;
    outF[aoff + t + 256] = o1;
    if (outB) { outB[aoff + t] = f2bf(o0); outB[aoff + t + 256] = f2bf(o1); }
}

extern "C" void kernel_launch(void* const* d_in, const int* in_sizes, int n_in,
                              void* d_out, int out_size, void* d_ws, size_t ws_size,
                              hipStream_t stream) {
    (void)in_sizes; (void)n_in; (void)out_size; (void)ws_size;
    const float* h       = (const float*)d_in[0];
    const float* arc_out = (const float*)d_in[1];
    const float* arc_in  = (const float*)d_in[2];
    const float* W_out_w = (const float*)d_in[4];
    const float* W_out_b = (const float*)d_in[5];
    const float* W_in_w  = (const float*)d_in[6];
    const float* W_in_b  = (const float*)d_in[7];
    const float* q_w  = (const float*)d_in[8];
    const float* q_b  = (const float*)d_in[9];
    const float* k_w  = (const float*)d_in[10];
    const float* k_b  = (const float*)d_in[11];
    const float* v_w  = (const float*)d_in[12];
    const float* v_b  = (const float*)d_in[13];
    const float* o_w  = (const float*)d_in[14];
    const float* o_b  = (const float*)d_in[15];
    const float* ln1_g = (const float*)d_in[16];
    const float* ln1_b = (const float*)d_in[17];
    const float* fc1_w = (const float*)d_in[18];
    const float* fc1_b = (const float*)d_in[19];
    const float* fc2_w = (const float*)d_in[20];
    const float* fc2_b = (const float*)d_in[21];
    const float* ln2_g = (const float*)d_in[22];
    const float* ln2_b = (const float*)d_in[23];
    float* out = (float*)d_out;

    char* wsb = (char*)d_ws;
    size_t off = 0;
    auto ALLOC = [&](size_t bytes) -> void* {
        void* ptr = wsb + off;
        off += (bytes + 255) & ~(size_t)255;
        return ptr;
    };
    unsigned short* WcatT = (unsigned short*)ALLOC((size_t)2560 * 512 * 2);
    unsigned short* W2to  = (unsigned short*)ALLOC(262144 * 2);
    unsigned short* W2ti  = (unsigned short*)ALLOC(262144 * 2);
    unsigned short* o_wT  = (unsigned short*)ALLOC(262144 * 2);
    unsigned short* v_wT  = (unsigned short*)ALLOC(262144 * 2);
    unsigned short* fc1T  = (unsigned short*)ALLOC((size_t)2048 * 512 * 2);
    unsigned short* fc2T  = (unsigned short*)ALLOC((size_t)512 * 2048 * 2);
    float* kwT   = (float*)ALLOC(262144 * 4);
    float* bias1 = (float*)ALLOC(2560 * 4);
    unsigned short* Qm = (unsigned short*)ALLOC(262144 * 2);
    float* QWcat = (float*)ALLOC((size_t)512 * 2560 * 4);
    unsigned short* pbuf = (unsigned short*)ALLOC((size_t)NTOK * 8 * 512 * 2);
    float* cbuf = (float*)ALLOC(NTOK * 8 * 4);
    unsigned short* Ubuf = (unsigned short*)ALLOC((size_t)NM * 512 * 2);
    float* Wsum = (float*)ALLOC((size_t)NTOK * 8 * 512 * 4);
    unsigned short* Waccb = (unsigned short*)ALLOC((size_t)NTOK * 8 * 512 * 2);
    unsigned short* tmpb  = (unsigned short*)ALLOC(262144 * 2);
    float* attsum = (float*)ALLOC(262144 * 4);
    float* x1  = (float*)ALLOC(262144 * 4);
    unsigned short* x1b = (unsigned short*)ALLOC(262144 * 2);
    unsigned short* ybb = (unsigned short*)ALLOC((size_t)NTOK * 2048 * 2);
    float* zparts = (float*)ALLOC((size_t)4 * 262144 * 4);

    k_prep<<<2058, 256, 0, stream>>>(h, Qm, k_w, kwT, W_out_b, W_in_b, q_b, bias1);

    // merged weight transposes (fp32 -> bf16 N x K)
    {
        TRJobs js = {};
        auto SET = [&](int i, const float* s, int sld, unsigned short* d, int dld,
                       float sc, int tiles, int tcols) {
            js.j[i] = TRJob{s, d, sld, dld, tcols, sc};
            js.start[i + 1] = js.start[i] + tiles;
        };
        js.start[0] = 0;
        SET(0,  W_out_w,              512, WcatT,              512, 1.f,    64, 8);
        SET(1,  W_out_w + 1024 * 512, 512, WcatT + 512 * 512,  512, 1.f,    64, 8);
        SET(2,  W_in_w,               512, WcatT + 1024 * 512, 512, 1.f,    64, 8);
        SET(3,  W_in_w + 1024 * 512,  512, WcatT + 1536 * 512, 512, 1.f,    64, 8);
        SET(4,  q_w,                  512, WcatT + 2048 * 512, 512, 0.125f, 64, 8);
        SET(5,  W_out_w + 512 * 512,  512, W2to,               512, 1.f,    64, 8);
        SET(6,  W_in_w + 512 * 512,   512, W2ti,               512, 1.f,    64, 8);
        SET(7,  o_w,                  512, o_wT,               512, 1.f,    64, 8);
        SET(8,  v_w,                  512, v_wT,               512, 1.f,    64, 8);
        SET(9,  fc1_w,               2048, fc1T,               512, 1.f,   256, 32);
        SET(10, fc2_w,                512, fc2T,              2048, 1.f,   256, 8);
        k_trN<<<js.start[11], 256, 0, stream>>>(js);
    }

    // batched Q-side projections: QWcat = Qm @ [W1o|W3o|W1i|W3i|q*.125] + bias1
    {
        MMP m = {};
        m.A = Qm; m.lda = 512; m.Bt = WcatT; m.ldb = 512;
        m.bias = bias1; m.biasScale = 1.f;
        m.outF = QWcat; m.ldo = 2560; m.K = 512;
        k_mm<<<dim3(8, 40), 256, 0, stream>>>(m);
    }
    k_prep2<<<dim3(64, 2), 256, 0, stream>>>(QWcat + 2048, 2560, kwT, k_b, pbuf, cbuf);

    for (int arc = 0; arc < 2; ++arc) {
        const float* arcp = (arc == 0) ? arc_out : arc_in;
        const unsigned short* w2 = (arc == 0) ? W2to : W2ti;
        const float* fixedM = (arc == 0) ? QWcat + 0    : QWcat + 1536;  // QW1o : QW3i
        const float* rowM   = (arc == 0) ? QWcat + 512  : QWcat + 1024;  // QW3o : QW1i
        k_midU<<<2048, 256, 0, stream>>>(arcp, w2, fixedM, 2560, rowM, 2560, Ubuf);
        k_att2<<<512, 256, 0, stream>>>(Ubuf, pbuf, cbuf, Wsum, Waccb, arc);
    }

    // Linear post-attention, summed over arcs:
    // att_out+att_in = ((Wacc0+Wacc1)@v_w per-head + 2*v_b)@o_w + 2*o_b
    {
        MMP m = {};
        m.A = Waccb; m.lda = 4096; m.aOffPerN64 = 512;
        m.Bt = v_wT; m.ldb = 512;
        m.bias = v_b; m.biasScale = 2.f;
        m.outB = tmpb; m.ldo = 512; m.K = 512;
        k_mm<<<dim3(8, 8), 256, 0, stream>>>(m);
    }
    {
        MMP m = {};
        m.A = tmpb; m.lda = 512; m.Bt = o_wT; m.ldb = 512;
        m.bias = o_b; m.biasScale = 2.f;
        m.outF = attsum; m.ldo = 512; m.K = 512;
        k_mm<<<dim3(8, 8), 256, 0, stream>>>(m);
    }

    k_ln<<<512, 256, 0, stream>>>(h, attsum, 1, nullptr, nullptr, ln1_g, ln1_b, x1, x1b);

    {
        MMP m = {};
        m.A = x1b; m.lda = 512; m.Bt = fc1T; m.ldb = 512;
        m.bias = fc1_b; m.biasScale = 1.f;
        m.relu = 1; m.outB = ybb; m.ldo = 2048; m.K = 512;
        k_mm<<<dim3(8, 32), 256, 0, stream>>>(m);
    }
    {
        MMP m = {};
        m.A = ybb; m.lda = 2048; m.Bt = fc2T; m.ldb = 2048;
        m.outF = zparts; m.ldo = 512; m.K = 512;
        m.zKOff = 512; m.zOutOff = 262144;
        k_mm<<<dim3(8, 8, 4), 256, 0, stream>>>(m);
    }
    k_ln<<<512, 256, 0, stream>>>(x1, nullptr, 0, zparts, fc2_b, ln2_g, ln2_b, out, nullptr);
}

// Round 12
// 349.181 us; speedup vs baseline: 1.5207x; 1.5207x over previous
//
#include <hip/hip_runtime.h>
#include <stdint.h>
#include <stddef.h>

// Shapes: D=512, F=2048, H=8, L=128, B=4
#define NTOK 512      // B*L tokens
#define NM   65536    // B*L*L edge rows

typedef __bf16 bf16x8 __attribute__((ext_vector_type(8)));
typedef float  f32x4  __attribute__((ext_vector_type(4)));
typedef unsigned int u32x4 __attribute__((ext_vector_type(4)));

__device__ __forceinline__ unsigned short f2bf(float f) {
    unsigned int u = __builtin_bit_cast(unsigned int, f);
    u += 0x7FFFu + ((u >> 16) & 1u);
    return (unsigned short)(u >> 16);
}
__device__ __forceinline__ float bf2f(unsigned short s) {
    unsigned int u = ((unsigned int)s) << 16;
    return __builtin_bit_cast(float, u);
}

// async global->LDS, 16B per lane; LDS dest is wave-uniform base + lane*16
__device__ __forceinline__ void gload16(const void* g, void* l) {
    __builtin_amdgcn_global_load_lds(
        (const __attribute__((address_space(1))) void*)g,
        (__attribute__((address_space(3))) void*)l,
        16, 0, 0);
}

// ---------- merged prep: h-transpose + k_w transpose + concat bias ----------
__global__ __launch_bounds__(256) void k_prep(const float* __restrict__ h,
                                              unsigned short* __restrict__ Qm,
                                              const float* __restrict__ kw,
                                              float* __restrict__ kwT,
                                              const float* __restrict__ Wob,
                                              const float* __restrict__ Wib,
                                              const float* __restrict__ qb,
                                              float* __restrict__ bias1) {
    int bid = blockIdx.x;
    int t = threadIdx.x;
    if (bid < 1024) {                       // h (L,B,D) -> Qm bf16 (b*128+i, 512)
        int idx = bid * 256 + t;
        int tok = idx >> 9, d = idx & 511;
        int b = tok >> 7, i = tok & 127;
        Qm[idx] = f2bf(h[(i * 4 + b) * 512 + d]);
    } else if (bid < 2048) {                // kwT[e][d] = k_w[d][e]
        int idx = (bid - 1024) * 256 + t;
        kwT[idx] = kw[(size_t)(idx & 511) * 512 + (idx >> 9)];
    } else {                                // bias1 concat
        int i = (bid - 2048) * 256 + t;
        if (i < 2560) {
            float v = 0.f;
            if (i < 512) v = Wob[i];
            else if (i < 1024) v = 0.f;
            else if (i < 1536) v = Wib[i - 1024];
            else if (i < 2048) v = 0.f;
            else v = qb[i - 2048] * 0.125f;
            bias1[i] = v;
        }
    }
}

// ---------- merged LDS-tiled fp32 -> bf16 transposes (job table) ----------
struct TRJob { const float* src; unsigned short* dst; int srcLd, dstLd, tcols; float scale; };
struct TRJobs { TRJob j[11]; int start[12]; };

__global__ __launch_bounds__(256) void k_trN(TRJobs js) {
    __shared__ float tile[64][65];
    int b = blockIdx.x;
    int ji = 0;
    while (ji < 10 && b >= js.start[ji + 1]) ++ji;
    TRJob jb = js.j[ji];
    int rel = b - js.start[ji];
    int bx = rel % jb.tcols, by = rel / jb.tcols;
    int r0 = by * 64, c0 = bx * 64;
    int t = threadIdx.x;
    int c = t & 63, rr = t >> 6;                // rr in 0..3
    #pragma unroll
    for (int ii = 0; ii < 16; ++ii) {
        int r = ii * 4 + rr;
        tile[r][c] = jb.src[(size_t)(r0 + r) * jb.srcLd + c0 + c];
    }
    __syncthreads();
    #pragma unroll
    for (int ii = 0; ii < 16; ++ii) {
        int n = ii * 4 + rr;                    // local col of src = row of dst
        jb.dst[(size_t)(c0 + n) * jb.dstLd + r0 + c] = f2bf(tile[c][n] * jb.scale);
    }
}

// ---------- generic bf16 MFMA GEMM: out = relu(A@B^T + bias*biasScale) [+accs] ----------
struct MMP {
    const unsigned short* A;  int lda;
    const unsigned short* Bt; int ldb;
    const float* bias;
    const float* accs;
    float* outF;
    unsigned short* outB;
    int ldo;
    int K;
    int relu;
    int aOffPerN64;
    int zKOff;
    int zOutOff;
    float biasScale;
};

__global__ __launch_bounds__(256) void k_mm(MMP p) {
    __shared__ unsigned char As[64 * 128];
    __shared__ unsigned char Bs[64 * 128];
    int t = threadIdx.x;
    int lane = t & 63, w = t >> 6;
    int m0 = blockIdx.x * 64, n0 = blockIdx.y * 64;
    int z = blockIdx.z;
    const unsigned short* A  = p.A + (size_t)(n0 >> 6) * p.aOffPerN64 + (size_t)z * p.zKOff;
    const unsigned short* Bt = p.Bt + (size_t)z * p.zKOff;
    int wm = (w >> 1) * 32, wn = (w & 1) * 32;
    f32x4 acc[2][2];
    #pragma unroll
    for (int a = 0; a < 2; ++a)
        #pragma unroll
        for (int b = 0; b < 2; ++b) acc[a][b] = (f32x4){0.f, 0.f, 0.f, 0.f};

    for (int kb = 0; kb < p.K; kb += 64) {
        __syncthreads();
        #pragma unroll
        for (int s = 0; s < 2; ++s) {
            int c = t + s * 256;
            int r = c >> 3, kc = (c & 7) * 8;
            int off = (r * 128 + kc * 2) ^ ((r & 7) << 4);
            *reinterpret_cast<u32x4*>(As + off) =
                *reinterpret_cast<const u32x4*>(A + (size_t)(m0 + r) * p.lda + kb + kc);
            *reinterpret_cast<u32x4*>(Bs + off) =
                *reinterpret_cast<const u32x4*>(Bt + (size_t)(n0 + r) * p.ldb + kb + kc);
        }
        __syncthreads();
        #pragma unroll
        for (int kh = 0; kh < 2; ++kh) {
            int kk = kh * 32 + (lane >> 4) * 8;
            bf16x8 af[2], bfr[2];
            #pragma unroll
            for (int mf = 0; mf < 2; ++mf) {
                int r = wm + mf * 16 + (lane & 15);
                int off = (r * 128 + kk * 2) ^ ((r & 7) << 4);
                af[mf] = *reinterpret_cast<const bf16x8*>(As + off);
            }
            #pragma unroll
            for (int nf = 0; nf < 2; ++nf) {
                int r = wn + nf * 16 + (lane & 15);
                int off = (r * 128 + kk * 2) ^ ((r & 7) << 4);
                bfr[nf] = *reinterpret_cast<const bf16x8*>(Bs + off);
            }
            #pragma unroll
            for (int mf = 0; mf < 2; ++mf)
                #pragma unroll
                for (int nf = 0; nf < 2; ++nf)
                    acc[mf][nf] = __builtin_amdgcn_mfma_f32_16x16x32_bf16(
                        af[mf], bfr[nf], acc[mf][nf], 0, 0, 0);
        }
    }
    #pragma unroll
    for (int mf = 0; mf < 2; ++mf) {
        #pragma unroll
        for (int rr = 0; rr < 4; ++rr) {
            int gm = m0 + wm + mf * 16 + (lane >> 4) * 4 + rr;
            #pragma unroll
            for (int nf = 0; nf < 2; ++nf) {
                int e = n0 + wn + nf * 16 + (lane & 15);
                float v = acc[mf][nf][rr];
                if (p.bias) v += p.bias[e] * p.biasScale;
                if (p.relu) v = fmaxf(v, 0.f);
                if (p.accs) v += p.accs[(size_t)gm * p.ldo + e];
                size_t oo = (size_t)gm * p.ldo + e + (size_t)z * p.zOutOff;
                if (p.outF) p.outF[oo] = v;
                if (p.outB) p.outB[oo] = f2bf(v);
            }
        }
    }
}

// ---------- p[tok][h][d] = sum_dh kwT[h*64+dh][d]*qs[tok][h*64+dh]; c[tok][h] ----------
__global__ __launch_bounds__(256) void k_prep2(const float* __restrict__ qs, int qld,
                                               const float* __restrict__ kwT,
                                               const float* __restrict__ k_b,
                                               unsigned short* __restrict__ p,
                                               float* __restrict__ c) {
    __shared__ float q8[8][512];
    int t = threadIdx.x;
    int tok0 = blockIdx.x * 8;
    int d = blockIdx.y * 256 + t;
    for (int idx = t; idx < 4096; idx += 256) {
        int s = idx >> 9, dd = idx & 511;
        q8[s][dd] = qs[(size_t)(tok0 + s) * qld + dd];
    }
    __syncthreads();
    if (blockIdx.y == 0 && t < 64) {
        int s = t >> 3, hh = t & 7;
        float cv = 0.f;
        for (int dh = 0; dh < 64; ++dh) cv += k_b[hh * 64 + dh] * q8[s][hh * 64 + dh];
        c[(tok0 + s) * 8 + hh] = cv;
    }
    for (int hh = 0; hh < 8; ++hh) {
        float pv[8];
        #pragma unroll
        for (int s = 0; s < 8; ++s) pv[s] = 0.f;
        for (int dh = 0; dh < 64; ++dh) {
            float wv = kwT[(size_t)(hh * 64 + dh) * 512 + d];
            #pragma unroll
            for (int s = 0; s < 8; ++s) pv[s] += wv * q8[s][hh * 64 + dh];
        }
        #pragma unroll
        for (int s = 0; s < 8; ++s)
            p[((size_t)(tok0 + s) * 8 + hh) * 512 + d] = f2bf(pv[s]);
    }
}

// ---------- edge MLP: U = relu(fixed[tokI] + arc@W2 + row[tokJ]) -> bf16 ----------
// BK=32 double-buffered gload_lds with COUNTED vmcnt (T3+T4) at the SAME 48KB
// LDS footprint as the best single-buffer version: 2x(16KB fp32 A + 8KB bf16 B),
// 16 K-steps, 6 gloads/wave/step, vmcnt(6) so next step's loads stay in flight
// across both barriers. Swizzle: involution on global source + on LDS reads.
__global__ __launch_bounds__(256) void k_midU(const float* __restrict__ arc,
                                              const unsigned short* __restrict__ W2t,
                                              const float* __restrict__ fixedMat, int fld,
                                              const float* __restrict__ rowMat, int rld,
                                              unsigned short* __restrict__ U) {
    __shared__ float As4[2][128 * 32];            // 2 x 16KB fp32 A
    __shared__ unsigned short Bs2[2][128 * 32];   // 2 x 8KB bf16 B
    int t = threadIdx.x;
    int lane = t & 63;
    int w = t >> 6;
    int bid = blockIdx.x;
    int xcd = bid & 7, slot = bid >> 3;          // round-robin XCD dispatch
    int mt = xcd * 64 + (slot >> 2);             // 0..511 m-tile
    int nt = slot & 3;                           // 4 n-siblings adjacent on one XCD
    int m0 = mt * 128, n0 = nt * 128;
    int wm = (w >> 1) * 64, wn = (w & 1) * 64;
    f32x4 acc[4][4];
    #pragma unroll
    for (int a = 0; a < 4; ++a)
        #pragma unroll
        for (int bq = 0; bq < 4; ++bq) acc[a][bq] = (f32x4){0.f, 0.f, 0.f, 0.f};

    // staging geometry (per wave per step: 4 A-issues + 2 B-issues = 6)
    int arA = lane >> 3;                 // A: row within 8-row group (128B rows)
    int acb = lane & 7;                  // A: 16B chunk within 128B row
    int brB = lane >> 2;                 // B: row within 16-row group (64B rows)
    int bcb = lane & 3;                  // B: 16B chunk within 64B row

#define ISSUE(KB, BUF)                                                          \
    _Pragma("unroll")                                                           \
    for (int i = 0; i < 4; ++i) {                                               \
        int base = (w * 4 + i) * 1024;                                          \
        int r = ((w * 4 + i) << 3) + arA;                                       \
        int cs = acb ^ (r & 7);                                                 \
        gload16(arc + (size_t)(m0 + r) * 512 + (KB) + cs * 4,                   \
                (char*)As4[BUF] + base);                                        \
    }                                                                           \
    _Pragma("unroll")                                                           \
    for (int i = 0; i < 2; ++i) {                                               \
        int base = (w * 2 + i) * 1024;                                          \
        int r = ((w * 2 + i) << 4) + brB;                                       \
        int cs = bcb ^ (r & 3);                                                 \
        gload16(W2t + (size_t)(n0 + r) * 512 + (KB) + cs * 8,                   \
                (char*)Bs2[BUF] + base);                                        \
    }

    ISSUE(0, 0);
    #pragma unroll
    for (int s = 0; s < 16; ++s) {
        int cur = s & 1;
        if (s < 15) {
            ISSUE((s + 1) * 32, cur ^ 1);        // next step's loads in flight
            asm volatile("s_waitcnt vmcnt(6)" ::: "memory");  // only cur's landed
        } else {
            asm volatile("s_waitcnt vmcnt(0)" ::: "memory");
        }
        __builtin_amdgcn_s_barrier();            // all waves' cur loads visible
        {
            int kk = (lane >> 4) * 8;            // fp32/bf16 k-col within 32
            bf16x8 af[4], bfr[4];
            #pragma unroll
            for (int mf = 0; mf < 4; ++mf) {
                int rr = wm + mf * 16 + (lane & 15);
                int c0 = kk >> 2;                // 16B chunk of fp32 row (0,2,4,6)
                const char* bp = (const char*)As4[cur] + rr * 128;
                float4 a0 = *reinterpret_cast<const float4*>(bp + ((c0 ^ (rr & 7)) << 4));
                float4 a1 = *reinterpret_cast<const float4*>(bp + (((c0 + 1) ^ (rr & 7)) << 4));
                af[mf][0] = (__bf16)a0.x; af[mf][1] = (__bf16)a0.y;
                af[mf][2] = (__bf16)a0.z; af[mf][3] = (__bf16)a0.w;
                af[mf][4] = (__bf16)a1.x; af[mf][5] = (__bf16)a1.y;
                af[mf][6] = (__bf16)a1.z; af[mf][7] = (__bf16)a1.w;
            }
            #pragma unroll
            for (int nf = 0; nf < 4; ++nf) {
                int rn = wn + nf * 16 + (lane & 15);
                int c = kk >> 3;                 // 16B chunk of bf16 row (0..3)
                bfr[nf] = *reinterpret_cast<const bf16x8*>(
                    (const char*)Bs2[cur] + rn * 64 + ((c ^ (rn & 3)) << 4));
            }
            #pragma unroll
            for (int mf = 0; mf < 4; ++mf)
                #pragma unroll
                for (int nf = 0; nf < 4; ++nf)
                    acc[mf][nf] = __builtin_amdgcn_mfma_f32_16x16x32_bf16(
                        af[mf], bfr[nf], acc[mf][nf], 0, 0, 0);
        }
        if (s < 15) __builtin_amdgcn_s_barrier();  // protect cur before reuse
    }
#undef ISSUE
    int tokI = mt;
    int bb = mt >> 7;
    float fx[4];
    #pragma unroll
    for (int nf = 0; nf < 4; ++nf)
        fx[nf] = fixedMat[(size_t)tokI * fld + n0 + wn + nf * 16 + (lane & 15)];
    #pragma unroll
    for (int mf = 0; mf < 4; ++mf) {
        #pragma unroll
        for (int r = 0; r < 4; ++r) {
            int row = wm + mf * 16 + (lane >> 4) * 4 + r;
            int gm = m0 + row;
            int tokJ = bb * 128 + (gm & 127);
            const float* rv = rowMat + (size_t)tokJ * rld;
            #pragma unroll
            for (int nf = 0; nf < 4; ++nf) {
                int e = n0 + wn + nf * 16 + (lane & 15);
                float v = acc[mf][nf][r] + fx[nf] + rv[e];
                v = fmaxf(v, 0.f);
                U[(size_t)gm * 512 + e] = f2bf(v);
            }
        }
    }
}

// ---------- fused scores+softmax+wacc (attn kept in 4KB LDS) ----------
// accum=0: Wsum (fp32) = attn@U ; accum=1: Waccb (bf16) = Wsum + attn@U
__global__ __launch_bounds__(256) void k_att2(const unsigned short* __restrict__ U,
                                              const unsigned short* __restrict__ p,
                                              const float* __restrict__ c,
                                              float* __restrict__ Wsum,
                                              unsigned short* __restrict__ Waccb,
                                              int accum) {
    __shared__ float at[8][128];
    int tok = blockIdx.x;
    int t = threadIdx.x;
    int w = t >> 6;
    int lane = t & 63;
    int hh = lane & 15;
    int kg = lane >> 4;
    bool hv = hh < 8;
    f32x4 acc[2];
    acc[0] = (f32x4){0.f, 0.f, 0.f, 0.f};
    acc[1] = (f32x4){0.f, 0.f, 0.f, 0.f};
    const unsigned short* Ub0 = U + (size_t)tok * 65536;
    const unsigned short* Ub = Ub0 + (size_t)(w * 32) * 512;
    const unsigned short* pb = p + ((size_t)tok * 8 + (hh & 7)) * 512;
    for (int ks = 0; ks < 16; ++ks) {
        int kcol = ks * 32 + kg * 8;
        u32x4 braw = (u32x4){0u, 0u, 0u, 0u};
        if (hv) braw = *reinterpret_cast<const u32x4*>(pb + kcol);
        bf16x8 bfrag = __builtin_bit_cast(bf16x8, braw);
        #pragma unroll
        for (int mf = 0; mf < 2; ++mf) {
            bf16x8 afrag = *reinterpret_cast<const bf16x8*>(
                Ub + (size_t)(mf * 16 + hh) * 512 + kcol);
            acc[mf] = __builtin_amdgcn_mfma_f32_16x16x32_bf16(afrag, bfrag, acc[mf], 0, 0, 0);
        }
    }
    if (hv) {
        float cval = c[tok * 8 + hh];
        #pragma unroll
        for (int mf = 0; mf < 2; ++mf)
            #pragma unroll
            for (int r = 0; r < 4; ++r)
                at[hh][w * 32 + mf * 16 + kg * 4 + r] = acc[mf][r] + cval;
    }
    __syncthreads();
    // softmax in place over j per head (8 groups x 32 lanes)
    {
        int h2 = t >> 5, l32 = t & 31;
        float v0 = at[h2][l32], v1 = at[h2][l32 + 32],
              v2 = at[h2][l32 + 64], v3 = at[h2][l32 + 96];
        float mx = fmaxf(fmaxf(v0, v1), fmaxf(v2, v3));
        #pragma unroll
        for (int o = 16; o >= 1; o >>= 1) mx = fmaxf(mx, __shfl_xor(mx, o));
        float e0 = __expf(v0 - mx), e1 = __expf(v1 - mx),
              e2 = __expf(v2 - mx), e3 = __expf(v3 - mx);
        float sum = e0 + e1 + e2 + e3;
        #pragma unroll
        for (int o = 16; o >= 1; o >>= 1) sum += __shfl_xor(sum, o);
        float inv = 1.f / sum;
        at[h2][l32]      = e0 * inv;
        at[h2][l32 + 32] = e1 * inv;
        at[h2][l32 + 64] = e2 * inv;
        at[h2][l32 + 96] = e3 * inv;
    }
    __syncthreads();
    // wacc: thread t covers d0=2t, all 8 heads; U re-read (L2/L3-hot)
    int d0 = t * 2;
    float a8[8][2];
    #pragma unroll
    for (int q = 0; q < 8; ++q) { a8[q][0] = 0.f; a8[q][1] = 0.f; }
    for (int j = 0; j < 128; ++j) {
        unsigned int uv = *reinterpret_cast<const unsigned int*>(Ub0 + (size_t)j * 512 + d0);
        float u0 = bf2f((unsigned short)(uv & 0xffffu));
        float u1 = bf2f((unsigned short)(uv >> 16));
        #pragma unroll
        for (int q = 0; q < 8; ++q) {
            float a = at[q][j];
            a8[q][0] += a * u0;
            a8[q][1] += a * u1;
        }
    }
    #pragma unroll
    for (int q = 0; q < 8; ++q) {
        size_t woff = ((size_t)tok * 8 + q) * 512 + d0;
        if (!accum) {
            Wsum[woff] = a8[q][0];
            Wsum[woff + 1] = a8[q][1];
        } else {
            float s0 = Wsum[woff] + a8[q][0];
            float s1 = Wsum[woff + 1] + a8[q][1];
            Waccb[woff] = f2bf(s0);
            Waccb[woff + 1] = f2bf(s1);
        }
    }
}

// ---------- layernorm: out = LN(A + B) * g + beta ----------
__global__ __launch_bounds__(256) void k_ln(const float* __restrict__ A,
                                            const float* __restrict__ Bv, int bswap,
                                            const float* __restrict__ parts,
                                            const float* __restrict__ pbias,
                                            const float* __restrict__ g,
                                            const float* __restrict__ bta,
                                            float* __restrict__ outF,
                                            unsigned short* __restrict__ outB) {
    int t = threadIdx.x;
    int tok = blockIdx.x;
    size_t aoff = (size_t)tok * 512;
    float b0, b1;
    if (parts) {
        b0 = parts[aoff + t] + parts[262144 + aoff + t] +
             parts[524288 + aoff + t] + parts[786432 + aoff + t] + pbias[t];
        b1 = parts[aoff + t + 256] + parts[262144 + aoff + t + 256] +
             parts[524288 + aoff + t + 256] + parts[786432 + aoff + t + 256] + pbias[t + 256];
    } else {
        size_t boff = aoff;
        if (bswap) { int i = tok >> 2, b = tok & 3; boff = (size_t)(b * 128 + i) * 512; }
        b0 = Bv[boff + t];
        b1 = Bv[boff + t + 256];
    }
    float v0 = A[aoff + t] + b0;
    float v1 = A[aoff + t + 256] + b1;
    float s = v0 + v1, q = v0 * v0 + v1 * v1;
    #pragma unroll
    for (int o = 32; o >= 1; o >>= 1) { s += __shfl_xor(s, o); q += __shfl_xor(q, o); }
    __shared__ float red[8];
    int w = t >> 6, lane = t & 63;
    if (lane == 0) { red[w] = s; red[4 + w] = q; }
    __syncthreads();
    float ts = red[0] + red[1] + red[2] + red[3];
    float tq = red[4] + red[5] + red[6] + red[7];
    float mean = ts * (1.f / 512.f);
    float var = tq * (1.f / 512.f) - mean * mean;
    float inv = rsqrtf(var + 1e-5f);
    float o0 = (v0 - mean) * inv * g[t] + bta[t];
    float o1 = (v1 - mean) * inv * g[t + 256] + bta[t + 256];
    outF[aoff + t] = o0;
    outF[aoff + t + 256] = o1;
    if (outB) { outB[aoff + t] = f2bf(o0); outB[aoff + t + 256] = f2bf(o1); }
}

extern "C" void kernel_launch(void* const* d_in, const int* in_sizes, int n_in,
                              void* d_out, int out_size, void* d_ws, size_t ws_size,
                              hipStream_t stream) {
    (void)in_sizes; (void)n_in; (void)out_size; (void)ws_size;
    const float* h       = (const float*)d_in[0];
    const float* arc_out = (const float*)d_in[1];
    const float* arc_in  = (const float*)d_in[2];
    const float* W_out_w = (const float*)d_in[4];
    const float* W_out_b = (const float*)d_in[5];
    const float* W_in_w  = (const float*)d_in[6];
    const float* W_in_b  = (const float*)d_in[7];
    const float* q_w  = (const float*)d_in[8];
    const float* q_b  = (const float*)d_in[9];
    const float* k_w  = (const float*)d_in[10];
    const float* k_b  = (const float*)d_in[11];
    const float* v_w  = (const float*)d_in[12];
    const float* v_b  = (const float*)d_in[13];
    const float* o_w  = (const float*)d_in[14];
    const float* o_b  = (const float*)d_in[15];
    const float* ln1_g = (const float*)d_in[16];
    const float* ln1_b = (const float*)d_in[17];
    const float* fc1_w = (const float*)d_in[18];
    const float* fc1_b = (const float*)d_in[19];
    const float* fc2_w = (const float*)d_in[20];
    const float* fc2_b = (const float*)d_in[21];
    const float* ln2_g = (const float*)d_in[22];
    const float* ln2_b = (const float*)d_in[23];
    float* out = (float*)d_out;

    char* wsb = (char*)d_ws;
    size_t off = 0;
    auto ALLOC = [&](size_t bytes) -> void* {
        void* ptr = wsb + off;
        off += (bytes + 255) & ~(size_t)255;
        return ptr;
    };
    unsigned short* WcatT = (unsigned short*)ALLOC((size_t)2560 * 512 * 2);
    unsigned short* W2to  = (unsigned short*)ALLOC(262144 * 2);
    unsigned short* W2ti  = (unsigned short*)ALLOC(262144 * 2);
    unsigned short* o_wT  = (unsigned short*)ALLOC(262144 * 2);
    unsigned short* v_wT  = (unsigned short*)ALLOC(262144 * 2);
    unsigned short* fc1T  = (unsigned short*)ALLOC((size_t)2048 * 512 * 2);
    unsigned short* fc2T  = (unsigned short*)ALLOC((size_t)512 * 2048 * 2);
    float* kwT   = (float*)ALLOC(262144 * 4);
    float* bias1 = (float*)ALLOC(2560 * 4);
    unsigned short* Qm = (unsigned short*)ALLOC(262144 * 2);
    float* QWcat = (float*)ALLOC((size_t)512 * 2560 * 4);
    unsigned short* pbuf = (unsigned short*)ALLOC((size_t)NTOK * 8 * 512 * 2);
    float* cbuf = (float*)ALLOC(NTOK * 8 * 4);
    unsigned short* Ubuf = (unsigned short*)ALLOC((size_t)NM * 512 * 2);
    float* Wsum = (float*)ALLOC((size_t)NTOK * 8 * 512 * 4);
    unsigned short* Waccb = (unsigned short*)ALLOC((size_t)NTOK * 8 * 512 * 2);
    unsigned short* tmpb  = (unsigned short*)ALLOC(262144 * 2);
    float* attsum = (float*)ALLOC(262144 * 4);
    float* x1  = (float*)ALLOC(262144 * 4);
    unsigned short* x1b = (unsigned short*)ALLOC(262144 * 2);
    unsigned short* ybb = (unsigned short*)ALLOC((size_t)NTOK * 2048 * 2);
    float* zparts = (float*)ALLOC((size_t)4 * 262144 * 4);

    k_prep<<<2058, 256, 0, stream>>>(h, Qm, k_w, kwT, W_out_b, W_in_b, q_b, bias1);

    // merged weight transposes (fp32 -> bf16 N x K)
    {
        TRJobs js = {};
        auto SET = [&](int i, const float* s, int sld, unsigned short* d, int dld,
                       float sc, int tiles, int tcols) {
            js.j[i] = TRJob{s, d, sld, dld, tcols, sc};
            js.start[i + 1] = js.start[i] + tiles;
        };
        js.start[0] = 0;
        SET(0,  W_out_w,              512, WcatT,              512, 1.f,    64, 8);
        SET(1,  W_out_w + 1024 * 512, 512, WcatT + 512 * 512,  512, 1.f,    64, 8);
        SET(2,  W_in_w,               512, WcatT + 1024 * 512, 512, 1.f,    64, 8);
        SET(3,  W_in_w + 1024 * 512,  512, WcatT + 1536 * 512, 512, 1.f,    64, 8);
        SET(4,  q_w,                  512, WcatT + 2048 * 512, 512, 0.125f, 64, 8);
        SET(5,  W_out_w + 512 * 512,  512, W2to,               512, 1.f,    64, 8);
        SET(6,  W_in_w + 512 * 512,   512, W2ti,               512, 1.f,    64, 8);
        SET(7,  o_w,                  512, o_wT,               512, 1.f,    64, 8);
        SET(8,  v_w,                  512, v_wT,               512, 1.f,    64, 8);
        SET(9,  fc1_w,               2048, fc1T,               512, 1.f,   256, 32);
        SET(10, fc2_w,                512, fc2T,              2048, 1.f,   256, 8);
        k_trN<<<js.start[11], 256, 0, stream>>>(js);
    }

    // batched Q-side projections: QWcat = Qm @ [W1o|W3o|W1i|W3i|q*.125] + bias1
    {
        MMP m = {};
        m.A = Qm; m.lda = 512; m.Bt = WcatT; m.ldb = 512;
        m.bias = bias1; m.biasScale = 1.f;
        m.outF = QWcat; m.ldo = 2560; m.K = 512;
        k_mm<<<dim3(8, 40), 256, 0, stream>>>(m);
    }
    k_prep2<<<dim3(64, 2), 256, 0, stream>>>(QWcat + 2048, 2560, kwT, k_b, pbuf, cbuf);

    for (int arc = 0; arc < 2; ++arc) {
        const float* arcp = (arc == 0) ? arc_out : arc_in;
        const unsigned short* w2 = (arc == 0) ? W2to : W2ti;
        const float* fixedM = (arc == 0) ? QWcat + 0    : QWcat + 1536;  // QW1o : QW3i
        const float* rowM   = (arc == 0) ? QWcat + 512  : QWcat + 1024;  // QW3o : QW1i
        k_midU<<<2048, 256, 0, stream>>>(arcp, w2, fixedM, 2560, rowM, 2560, Ubuf);
        k_att2<<<512, 256, 0, stream>>>(Ubuf, pbuf, cbuf, Wsum, Waccb, arc);
    }

    // Linear post-attention, summed over arcs:
    // att_out+att_in = ((Wacc0+Wacc1)@v_w per-head + 2*v_b)@o_w + 2*o_b
    {
        MMP m = {};
        m.A = Waccb; m.lda = 4096; m.aOffPerN64 = 512;
        m.Bt = v_wT; m.ldb = 512;
        m.bias = v_b; m.biasScale = 2.f;
        m.outB = tmpb; m.ldo = 512; m.K = 512;
        k_mm<<<dim3(8, 8), 256, 0, stream>>>(m);
    }
    {
        MMP m = {};
        m.A = tmpb; m.lda = 512; m.Bt = o_wT; m.ldb = 512;
        m.bias = o_b; m.biasScale = 2.f;
        m.outF = attsum; m.ldo = 512; m.K = 512;
        k_mm<<<dim3(8, 8), 256, 0, stream>>>(m);
    }

    k_ln<<<512, 256, 0, stream>>>(h, attsum, 1, nullptr, nullptr, ln1_g, ln1_b, x1, x1b);

    {
        MMP m = {};
        m.A = x1b; m.lda = 512; m.Bt = fc1T; m.ldb = 512;
        m.bias = fc1_b; m.biasScale = 1.f;
        m.relu = 1; m.outB = ybb; m.ldo = 2048; m.K = 512;
        k_mm<<<dim3(8, 32), 256, 0, stream>>>(m);
    }
    {
        MMP m = {};
        m.A = ybb; m.lda = 2048; m.Bt = fc2T; m.ldb = 2048;
        m.outF = zparts; m.ldo = 512; m.K = 512;
        m.zKOff = 512; m.zOutOff = 262144;
        k_mm<<<dim3(8, 8, 4), 256, 0, stream>>>(m);
    }
    k_ln<<<512, 256, 0, stream>>>(x1, nullptr, 0, zparts, fc2_b, ln2_g, ln2_b, out, nullptr);
}

// Round 13
// 344.932 us; speedup vs baseline: 1.5394x; 1.0123x over previous
//
#include <hip/hip_runtime.h>
#include <stdint.h>
#include <stddef.h>

// Shapes: D=512, F=2048, H=8, L=128, B=4
#define NTOK 512      // B*L tokens
#define NM   65536    // B*L*L edge rows

typedef __bf16 bf16x8 __attribute__((ext_vector_type(8)));
typedef float  f32x4  __attribute__((ext_vector_type(4)));
typedef unsigned int u32x4 __attribute__((ext_vector_type(4)));

__device__ __forceinline__ unsigned short f2bf(float f) {
    unsigned int u = __builtin_bit_cast(unsigned int, f);
    u += 0x7FFFu + ((u >> 16) & 1u);
    return (unsigned short)(u >> 16);
}
__device__ __forceinline__ float bf2f(unsigned short s) {
    unsigned int u = ((unsigned int)s) << 16;
    return __builtin_bit_cast(float, u);
}

// async global->LDS, 16B per lane; LDS dest is wave-uniform base + lane*16
__device__ __forceinline__ void gload16(const void* g, void* l) {
    __builtin_amdgcn_global_load_lds(
        (const __attribute__((address_space(1))) void*)g,
        (__attribute__((address_space(3))) void*)l,
        16, 0, 0);
}

// ---------- merged prep + weight transposes (independent work, one launch) ----------
struct TRJob { const float* src; unsigned short* dst; int srcLd, dstLd, tcols; float scale; };
struct PrepArgs {
    const float* h; unsigned short* Qm;
    const float* kw; float* kwT;
    const float* Wob; const float* Wib; const float* qb; float* bias1;
    TRJob j[11]; int start[12];
};

__global__ __launch_bounds__(256) void k_prepAll(PrepArgs a) {
    __shared__ float tile[64][65];
    int bid = blockIdx.x;
    int t = threadIdx.x;
    if (bid < 1024) {                       // h (L,B,D) -> Qm bf16 (b*128+i, 512)
        int idx = bid * 256 + t;
        int tok = idx >> 9, d = idx & 511;
        int b = tok >> 7, i = tok & 127;
        a.Qm[idx] = f2bf(a.h[(i * 4 + b) * 512 + d]);
        return;
    } else if (bid < 2048) {                // kwT[e][d] = k_w[d][e]
        int idx = (bid - 1024) * 256 + t;
        a.kwT[idx] = a.kw[(size_t)(idx & 511) * 512 + (idx >> 9)];
        return;
    } else if (bid < 2058) {                // bias1 concat
        int i = (bid - 2048) * 256 + t;
        if (i < 2560) {
            float v = 0.f;
            if (i < 512) v = a.Wob[i];
            else if (i < 1024) v = 0.f;
            else if (i < 1536) v = a.Wib[i - 1024];
            else if (i < 2048) v = 0.f;
            else v = a.qb[i - 2048] * 0.125f;
            a.bias1[i] = v;
        }
        return;
    }
    // weight transpose tiles
    int b = bid - 2058;
    int ji = 0;
    while (ji < 10 && b >= a.start[ji + 1]) ++ji;
    TRJob jb = a.j[ji];
    int rel = b - a.start[ji];
    int bx = rel % jb.tcols, by = rel / jb.tcols;
    int r0 = by * 64, c0 = bx * 64;
    int c = t & 63, rr = t >> 6;
    #pragma unroll
    for (int ii = 0; ii < 16; ++ii) {
        int r = ii * 4 + rr;
        tile[r][c] = jb.src[(size_t)(r0 + r) * jb.srcLd + c0 + c];
    }
    __syncthreads();
    #pragma unroll
    for (int ii = 0; ii < 16; ++ii) {
        int n = ii * 4 + rr;
        jb.dst[(size_t)(c0 + n) * jb.dstLd + r0 + c] = f2bf(tile[c][n] * jb.scale);
    }
}

// ---------- generic bf16 MFMA GEMM: out = relu(A@B^T + bias*biasScale) [+accs] ----------
// Optional fused fp32-sum A path: A := bf16(Af2a + Af2b) staged on the fly.
struct MMP {
    const unsigned short* A;  int lda;
    const float* Af2a; const float* Af2b; int ldaf;
    const unsigned short* Bt; int ldb;
    const float* bias;
    const float* accs;
    float* outF;
    unsigned short* outB;
    int ldo;
    int K;
    int relu;
    int aOffPerN64;
    int zKOff;
    int zOutOff;
    float biasScale;
};

__global__ __launch_bounds__(256) void k_mm(MMP p) {
    __shared__ unsigned char As[64 * 128];
    __shared__ unsigned char Bs[64 * 128];
    int t = threadIdx.x;
    int lane = t & 63, w = t >> 6;
    int m0 = blockIdx.x * 64, n0 = blockIdx.y * 64;
    int z = blockIdx.z;
    size_t aoffel = (size_t)(n0 >> 6) * p.aOffPerN64 + (size_t)z * p.zKOff;
    const unsigned short* A  = p.A + aoffel;
    const unsigned short* Bt = p.Bt + (size_t)z * p.zKOff;
    int wm = (w >> 1) * 32, wn = (w & 1) * 32;
    f32x4 acc[2][2];
    #pragma unroll
    for (int a = 0; a < 2; ++a)
        #pragma unroll
        for (int b = 0; b < 2; ++b) acc[a][b] = (f32x4){0.f, 0.f, 0.f, 0.f};

    for (int kb = 0; kb < p.K; kb += 64) {
        __syncthreads();
        #pragma unroll
        for (int s = 0; s < 2; ++s) {
            int c = t + s * 256;
            int r = c >> 3, kc = (c & 7) * 8;
            int off = (r * 128 + kc * 2) ^ ((r & 7) << 4);
            if (p.Af2a) {
                size_t ro = aoffel + (size_t)(m0 + r) * p.ldaf + kb + kc;
                const float4* xa = reinterpret_cast<const float4*>(p.Af2a + ro);
                const float4* ya = reinterpret_cast<const float4*>(p.Af2b + ro);
                float4 x0 = xa[0], x1 = xa[1], y0 = ya[0], y1 = ya[1];
                bf16x8 bv;
                bv[0] = (__bf16)(x0.x + y0.x); bv[1] = (__bf16)(x0.y + y0.y);
                bv[2] = (__bf16)(x0.z + y0.z); bv[3] = (__bf16)(x0.w + y0.w);
                bv[4] = (__bf16)(x1.x + y1.x); bv[5] = (__bf16)(x1.y + y1.y);
                bv[6] = (__bf16)(x1.z + y1.z); bv[7] = (__bf16)(x1.w + y1.w);
                *reinterpret_cast<bf16x8*>(As + off) = bv;
            } else {
                *reinterpret_cast<u32x4*>(As + off) =
                    *reinterpret_cast<const u32x4*>(A + (size_t)(m0 + r) * p.lda + kb + kc);
            }
            *reinterpret_cast<u32x4*>(Bs + off) =
                *reinterpret_cast<const u32x4*>(Bt + (size_t)(n0 + r) * p.ldb + kb + kc);
        }
        __syncthreads();
        #pragma unroll
        for (int kh = 0; kh < 2; ++kh) {
            int kk = kh * 32 + (lane >> 4) * 8;
            bf16x8 af[2], bfr[2];
            #pragma unroll
            for (int mf = 0; mf < 2; ++mf) {
                int r = wm + mf * 16 + (lane & 15);
                int off = (r * 128 + kk * 2) ^ ((r & 7) << 4);
                af[mf] = *reinterpret_cast<const bf16x8*>(As + off);
            }
            #pragma unroll
            for (int nf = 0; nf < 2; ++nf) {
                int r = wn + nf * 16 + (lane & 15);
                int off = (r * 128 + kk * 2) ^ ((r & 7) << 4);
                bfr[nf] = *reinterpret_cast<const bf16x8*>(Bs + off);
            }
            #pragma unroll
            for (int mf = 0; mf < 2; ++mf)
                #pragma unroll
                for (int nf = 0; nf < 2; ++nf)
                    acc[mf][nf] = __builtin_amdgcn_mfma_f32_16x16x32_bf16(
                        af[mf], bfr[nf], acc[mf][nf], 0, 0, 0);
        }
    }
    #pragma unroll
    for (int mf = 0; mf < 2; ++mf) {
        #pragma unroll
        for (int rr = 0; rr < 4; ++rr) {
            int gm = m0 + wm + mf * 16 + (lane >> 4) * 4 + rr;
            #pragma unroll
            for (int nf = 0; nf < 2; ++nf) {
                int e = n0 + wn + nf * 16 + (lane & 15);
                float v = acc[mf][nf][rr];
                if (p.bias) v += p.bias[e] * p.biasScale;
                if (p.relu) v = fmaxf(v, 0.f);
                if (p.accs) v += p.accs[(size_t)gm * p.ldo + e];
                size_t oo = (size_t)gm * p.ldo + e + (size_t)z * p.zOutOff;
                if (p.outF) p.outF[oo] = v;
                if (p.outB) p.outB[oo] = f2bf(v);
            }
        }
    }
}

// ---------- p[tok][h][d] = sum_dh kwT[h*64+dh][d]*qs[tok][h*64+dh]; c[tok][h] ----------
__global__ __launch_bounds__(256) void k_prep2(const float* __restrict__ qs, int qld,
                                               const float* __restrict__ kwT,
                                               const float* __restrict__ k_b,
                                               unsigned short* __restrict__ p,
                                               float* __restrict__ c) {
    __shared__ float q8[8][512];
    int t = threadIdx.x;
    int tok0 = blockIdx.x * 8;
    int d = blockIdx.y * 256 + t;
    for (int idx = t; idx < 4096; idx += 256) {
        int s = idx >> 9, dd = idx & 511;
        q8[s][dd] = qs[(size_t)(tok0 + s) * qld + dd];
    }
    __syncthreads();
    if (blockIdx.y == 0 && t < 64) {
        int s = t >> 3, hh = t & 7;
        float cv = 0.f;
        for (int dh = 0; dh < 64; ++dh) cv += k_b[hh * 64 + dh] * q8[s][hh * 64 + dh];
        c[(tok0 + s) * 8 + hh] = cv;
    }
    for (int hh = 0; hh < 8; ++hh) {
        float pv[8];
        #pragma unroll
        for (int s = 0; s < 8; ++s) pv[s] = 0.f;
        for (int dh = 0; dh < 64; ++dh) {
            float wv = kwT[(size_t)(hh * 64 + dh) * 512 + d];
            #pragma unroll
            for (int s = 0; s < 8; ++s) pv[s] += wv * q8[s][hh * 64 + dh];
        }
        #pragma unroll
        for (int s = 0; s < 8; ++s)
            p[((size_t)(tok0 + s) * 8 + hh) * 512 + d] = f2bf(pv[s]);
    }
}

// ---------- edge MLP, BOTH arcs in one dispatch (4096 blocks) ----------
// R10 structure (best measured: 105 us/arc): single-buffer gload_lds staging,
// A raw fp32 (no VGPR trip), cvt at fragment read; B bf16. Swizzle on global
// source + LDS reads (rule #21). xcd 0-3 -> arc_out, 4-7 -> arc_in.
__global__ __launch_bounds__(256) void k_midU(const float* __restrict__ arcO,
                                              const float* __restrict__ arcI,
                                              const unsigned short* __restrict__ W2to,
                                              const unsigned short* __restrict__ W2ti,
                                              const float* __restrict__ QWcat,
                                              unsigned short* __restrict__ U0,
                                              unsigned short* __restrict__ U1) {
    __shared__ float As4[128 * 64];            // 32KB fp32 A tile (swizzled storage)
    __shared__ unsigned short Bs2[128 * 64];   // 16KB bf16 B tile
    int t = threadIdx.x;
    int lane = t & 63;
    int w = t >> 6;
    int bid = blockIdx.x;
    int xcd = bid & 7, slot = bid >> 3;          // 512 slots per xcd
    int mtf = xcd * 128 + (slot >> 2);           // 0..1023 combined m-tile
    int nt = slot & 3;                           // 4 n-siblings adjacent on one XCD
    int arc01 = mtf >> 9;
    int mt = mtf & 511;
    const float* arc = arc01 ? arcI : arcO;
    const unsigned short* W2t = arc01 ? W2ti : W2to;
    const float* fixedMat = QWcat + (arc01 ? 1536 : 0);
    const float* rowMat   = QWcat + (arc01 ? 1024 : 512);
    unsigned short* U = arc01 ? U1 : U0;
    int m0 = mt * 128;
    int n0 = nt * 128;
    int wm = (w >> 1) * 64, wn = (w & 1) * 64;
    f32x4 acc[4][4];
    #pragma unroll
    for (int a = 0; a < 4; ++a)
        #pragma unroll
        for (int bq = 0; bq < 4; ++bq) acc[a][bq] = (f32x4){0.f, 0.f, 0.f, 0.f};

    int arA = lane >> 4;                 // A: row within 4-row group
    int acb = lane & 15;                 // A: 16B chunk within 256B row
    int brB = lane >> 3;                 // B: row within 8-row group
    int bcb = lane & 7;                  // B: 16B chunk within 128B row

    for (int kb8 = 0; kb8 < 8; ++kb8) {
        int kb = kb8 * 64;
        __syncthreads();
        #pragma unroll
        for (int i = 0; i < 8; ++i) {
            int base = (w * 8 + i) * 1024;
            int r = ((w * 8 + i) << 2) + arA;
            int cs = acb ^ (r & 7);
            gload16(arc + (size_t)(m0 + r) * 512 + kb + cs * 4,
                    (char*)As4 + base);
        }
        #pragma unroll
        for (int i = 0; i < 4; ++i) {
            int base = (w * 4 + i) * 1024;
            int r = ((w * 4 + i) << 3) + brB;
            int cs = bcb ^ (r & 7);
            gload16(W2t + (size_t)(n0 + r) * 512 + kb + cs * 8,
                    (char*)Bs2 + base);
        }
        __syncthreads();
        #pragma unroll
        for (int kh = 0; kh < 2; ++kh) {
            int kk = kh * 32 + (lane >> 4) * 8;
            bf16x8 af[4], bfr[4];
            #pragma unroll
            for (int mf = 0; mf < 4; ++mf) {
                int rr = wm + mf * 16 + (lane & 15);
                int c0 = kk >> 2;
                const char* bp = (const char*)As4 + rr * 256;
                float4 a0 = *reinterpret_cast<const float4*>(bp + ((c0 ^ (rr & 7)) << 4));
                float4 a1 = *reinterpret_cast<const float4*>(bp + (((c0 + 1) ^ (rr & 7)) << 4));
                af[mf][0] = (__bf16)a0.x; af[mf][1] = (__bf16)a0.y;
                af[mf][2] = (__bf16)a0.z; af[mf][3] = (__bf16)a0.w;
                af[mf][4] = (__bf16)a1.x; af[mf][5] = (__bf16)a1.y;
                af[mf][6] = (__bf16)a1.z; af[mf][7] = (__bf16)a1.w;
            }
            #pragma unroll
            for (int nf = 0; nf < 4; ++nf) {
                int rn = wn + nf * 16 + (lane & 15);
                int c = kk >> 3;
                bfr[nf] = *reinterpret_cast<const bf16x8*>(
                    (const char*)Bs2 + rn * 128 + ((c ^ (rn & 7)) << 4));
            }
            #pragma unroll
            for (int mf = 0; mf < 4; ++mf)
                #pragma unroll
                for (int nf = 0; nf < 4; ++nf)
                    acc[mf][nf] = __builtin_amdgcn_mfma_f32_16x16x32_bf16(
                        af[mf], bfr[nf], acc[mf][nf], 0, 0, 0);
        }
    }
    int tokI = mt;
    int bb = mt >> 7;
    float fx[4];
    #pragma unroll
    for (int nf = 0; nf < 4; ++nf)
        fx[nf] = fixedMat[(size_t)tokI * 2560 + n0 + wn + nf * 16 + (lane & 15)];
    #pragma unroll
    for (int mf = 0; mf < 4; ++mf) {
        #pragma unroll
        for (int r = 0; r < 4; ++r) {
            int row = wm + mf * 16 + (lane >> 4) * 4 + r;
            int gm = m0 + row;
            int tokJ = bb * 128 + (gm & 127);
            const float* rv = rowMat + (size_t)tokJ * 2560;
            #pragma unroll
            for (int nf = 0; nf < 4; ++nf) {
                int e = n0 + wn + nf * 16 + (lane & 15);
                float v = acc[mf][nf][r] + fx[nf] + rv[e];
                v = fmaxf(v, 0.f);
                U[(size_t)gm * 512 + e] = f2bf(v);
            }
        }
    }
}

// ---------- fused scores+softmax+wacc, BOTH arcs (1024 blocks) ----------
// arc = bid>>9; writes per-arc fp32 Wsum (no cross-arc ordering needed).
__global__ __launch_bounds__(256) void k_att2(const unsigned short* __restrict__ U0,
                                              const unsigned short* __restrict__ U1,
                                              const unsigned short* __restrict__ p,
                                              const float* __restrict__ c,
                                              float* __restrict__ Wsum0,
                                              float* __restrict__ Wsum1) {
    __shared__ float at[8][128];
    int bid = blockIdx.x;
    int arc01 = bid >> 9;
    int tok = bid & 511;
    const unsigned short* U = arc01 ? U1 : U0;
    float* Ws = arc01 ? Wsum1 : Wsum0;
    int t = threadIdx.x;
    int w = t >> 6;
    int lane = t & 63;
    int hh = lane & 15;
    int kg = lane >> 4;
    bool hv = hh < 8;
    f32x4 acc[2];
    acc[0] = (f32x4){0.f, 0.f, 0.f, 0.f};
    acc[1] = (f32x4){0.f, 0.f, 0.f, 0.f};
    const unsigned short* Ub0 = U + (size_t)tok * 65536;
    const unsigned short* Ub = Ub0 + (size_t)(w * 32) * 512;
    const unsigned short* pb = p + ((size_t)tok * 8 + (hh & 7)) * 512;
    for (int ks = 0; ks < 16; ++ks) {
        int kcol = ks * 32 + kg * 8;
        u32x4 braw = (u32x4){0u, 0u, 0u, 0u};
        if (hv) braw = *reinterpret_cast<const u32x4*>(pb + kcol);
        bf16x8 bfrag = __builtin_bit_cast(bf16x8, braw);
        #pragma unroll
        for (int mf = 0; mf < 2; ++mf) {
            bf16x8 afrag = *reinterpret_cast<const bf16x8*>(
                Ub + (size_t)(mf * 16 + hh) * 512 + kcol);
            acc[mf] = __builtin_amdgcn_mfma_f32_16x16x32_bf16(afrag, bfrag, acc[mf], 0, 0, 0);
        }
    }
    if (hv) {
        float cval = c[tok * 8 + hh];
        #pragma unroll
        for (int mf = 0; mf < 2; ++mf)
            #pragma unroll
            for (int r = 0; r < 4; ++r)
                at[hh][w * 32 + mf * 16 + kg * 4 + r] = acc[mf][r] + cval;
    }
    __syncthreads();
    {
        int h2 = t >> 5, l32 = t & 31;
        float v0 = at[h2][l32], v1 = at[h2][l32 + 32],
              v2 = at[h2][l32 + 64], v3 = at[h2][l32 + 96];
        float mx = fmaxf(fmaxf(v0, v1), fmaxf(v2, v3));
        #pragma unroll
        for (int o = 16; o >= 1; o >>= 1) mx = fmaxf(mx, __shfl_xor(mx, o));
        float e0 = __expf(v0 - mx), e1 = __expf(v1 - mx),
              e2 = __expf(v2 - mx), e3 = __expf(v3 - mx);
        float sum = e0 + e1 + e2 + e3;
        #pragma unroll
        for (int o = 16; o >= 1; o >>= 1) sum += __shfl_xor(sum, o);
        float inv = 1.f / sum;
        at[h2][l32]      = e0 * inv;
        at[h2][l32 + 32] = e1 * inv;
        at[h2][l32 + 64] = e2 * inv;
        at[h2][l32 + 96] = e3 * inv;
    }
    __syncthreads();
    int d0 = t * 2;
    float a8[8][2];
    #pragma unroll
    for (int q = 0; q < 8; ++q) { a8[q][0] = 0.f; a8[q][1] = 0.f; }
    for (int j = 0; j < 128; ++j) {
        unsigned int uv = *reinterpret_cast<const unsigned int*>(Ub0 + (size_t)j * 512 + d0);
        float u0 = bf2f((unsigned short)(uv & 0xffffu));
        float u1 = bf2f((unsigned short)(uv >> 16));
        #pragma unroll
        for (int q = 0; q < 8; ++q) {
            float a = at[q][j];
            a8[q][0] += a * u0;
            a8[q][1] += a * u1;
        }
    }
    #pragma unroll
    for (int q = 0; q < 8; ++q) {
        size_t woff = ((size_t)tok * 8 + q) * 512 + d0;
        Ws[woff] = a8[q][0];
        Ws[woff + 1] = a8[q][1];
    }
}

// ---------- layernorm: out = LN(A + B) * g + beta ----------
__global__ __launch_bounds__(256) void k_ln(const float* __restrict__ A,
                                            const float* __restrict__ Bv, int bswap,
                                            const float* __restrict__ parts,
                                            const float* __restrict__ pbias,
                                            const float* __restrict__ g,
                                            const float* __restrict__ bta,
                                            float* __restrict__ outF,
                                            unsigned short* __restrict__ outB) {
    int t = threadIdx.x;
    int tok = blockIdx.x;
    size_t aoff = (size_t)tok * 512;
    float b0, b1;
    if (parts) {
        b0 = parts[aoff + t] + parts[262144 + aoff + t] +
             parts[524288 + aoff + t] + parts[786432 + aoff + t] + pbias[t];
        b1 = parts[aoff + t + 256] + parts[262144 + aoff + t + 256] +
             parts[524288 + aoff + t + 256] + parts[786432 + aoff + t + 256] + pbias[t + 256];
    } else {
        size_t boff = aoff;
        if (bswap) { int i = tok >> 2, b = tok & 3; boff = (size_t)(b * 128 + i) * 512; }
        b0 = Bv[boff + t];
        b1 = Bv[boff + t + 256];
    }
    float v0 = A[aoff + t] + b0;
    float v1 = A[aoff + t + 256] + b1;
    float s = v0 + v1, q = v0 * v0 + v1 * v1;
    #pragma unroll
    for (int o = 32; o >= 1; o >>= 1) { s += __shfl_xor(s, o); q += __shfl_xor(q, o); }
    __shared__ float red[8];
    int w = t >> 6, lane = t & 63;
    if (lane == 0) { red[w] = s; red[4 + w] = q; }
    __syncthreads();
    float ts = red[0] + red[1] + red[2] + red[3];
    float tq = red[4] + red[5] + red[6] + red[7];
    float mean = ts * (1.f / 512.f);
    float var = tq * (1.f / 512.f) - mean * mean;
    float inv = rsqrtf(var + 1e-5f);
    float o0 = (v0 - mean) * inv * g[t] + bta[t];
    float o1 = (v1 - mean) * inv * g[t + 256] + bta[t + 256];
    outF[aoff + t] = o0;
    outF[aoff + t + 256] = o1;
    if (outB) { outB[aoff + t] = f2bf(o0); outB[aoff + t + 256] = f2bf(o1); }
}

extern "C" void kernel_launch(void* const* d_in, const int* in_sizes, int n_in,
                              void* d_out, int out_size, void* d_ws, size_t ws_size,
                              hipStream_t stream) {
    (void)in_sizes; (void)n_in; (void)out_size; (void)ws_size;
    const float* h       = (const float*)d_in[0];
    const float* arc_out = (const float*)d_in[1];
    const float* arc_in  = (const float*)d_in[2];
    const float* W_out_w = (const float*)d_in[4];
    const float* W_out_b = (const float*)d_in[5];
    const float* W_in_w  = (const float*)d_in[6];
    const float* W_in_b  = (const float*)d_in[7];
    const float* q_w  = (const float*)d_in[8];
    const float* q_b  = (const float*)d_in[9];
    const float* k_w  = (const float*)d_in[10];
    const float* k_b  = (const float*)d_in[11];
    const float* v_w  = (const float*)d_in[12];
    const float* v_b  = (const float*)d_in[13];
    const float* o_w  = (const float*)d_in[14];
    const float* o_b  = (const float*)d_in[15];
    const float* ln1_g = (const float*)d_in[16];
    const float* ln1_b = (const float*)d_in[17];
    const float* fc1_w = (const float*)d_in[18];
    const float* fc1_b = (const float*)d_in[19];
    const float* fc2_w = (const float*)d_in[20];
    const float* fc2_b = (const float*)d_in[21];
    const float* ln2_g = (const float*)d_in[22];
    const float* ln2_b = (const float*)d_in[23];
    float* out = (float*)d_out;

    char* wsb = (char*)d_ws;
    size_t off = 0;
    auto ALLOC = [&](size_t bytes) -> void* {
        void* ptr = wsb + off;
        off += (bytes + 255) & ~(size_t)255;
        return ptr;
    };
    unsigned short* WcatT = (unsigned short*)ALLOC((size_t)2560 * 512 * 2);
    unsigned short* W2to  = (unsigned short*)ALLOC(262144 * 2);
    unsigned short* W2ti  = (unsigned short*)ALLOC(262144 * 2);
    unsigned short* o_wT  = (unsigned short*)ALLOC(262144 * 2);
    unsigned short* v_wT  = (unsigned short*)ALLOC(262144 * 2);
    unsigned short* fc1T  = (unsigned short*)ALLOC((size_t)2048 * 512 * 2);
    unsigned short* fc2T  = (unsigned short*)ALLOC((size_t)512 * 2048 * 2);
    float* kwT   = (float*)ALLOC(262144 * 4);
    float* bias1 = (float*)ALLOC(2560 * 4);
    unsigned short* Qm = (unsigned short*)ALLOC(262144 * 2);
    float* QWcat = (float*)ALLOC((size_t)512 * 2560 * 4);
    unsigned short* pbuf = (unsigned short*)ALLOC((size_t)NTOK * 8 * 512 * 2);
    float* cbuf = (float*)ALLOC(NTOK * 8 * 4);
    unsigned short* Ubuf0 = (unsigned short*)ALLOC((size_t)NM * 512 * 2);
    unsigned short* Ubuf1 = (unsigned short*)ALLOC((size_t)NM * 512 * 2);
    float* Wsum0 = (float*)ALLOC((size_t)NTOK * 8 * 512 * 4);
    float* Wsum1 = (float*)ALLOC((size_t)NTOK * 8 * 512 * 4);
    unsigned short* tmpb  = (unsigned short*)ALLOC(262144 * 2);
    float* attsum = (float*)ALLOC(262144 * 4);
    float* x1  = (float*)ALLOC(262144 * 4);
    unsigned short* x1b = (unsigned short*)ALLOC(262144 * 2);
    unsigned short* ybb = (unsigned short*)ALLOC((size_t)NTOK * 2048 * 2);
    float* zparts = (float*)ALLOC((size_t)4 * 262144 * 4);

    // merged prep + transposes (single launch)
    {
        PrepArgs a = {};
        a.h = h; a.Qm = Qm; a.kw = k_w; a.kwT = kwT;
        a.Wob = W_out_b; a.Wib = W_in_b; a.qb = q_b; a.bias1 = bias1;
        auto SET = [&](int i, const float* s, int sld, unsigned short* d, int dld,
                       float sc, int tiles, int tcols) {
            a.j[i] = TRJob{s, d, sld, dld, tcols, sc};
            a.start[i + 1] = a.start[i] + tiles;
        };
        a.start[0] = 0;
        SET(0,  W_out_w,              512, WcatT,              512, 1.f,    64, 8);
        SET(1,  W_out_w + 1024 * 512, 512, WcatT + 512 * 512,  512, 1.f,    64, 8);
        SET(2,  W_in_w,               512, WcatT + 1024 * 512, 512, 1.f,    64, 8);
        SET(3,  W_in_w + 1024 * 512,  512, WcatT + 1536 * 512, 512, 1.f,    64, 8);
        SET(4,  q_w,                  512, WcatT + 2048 * 512, 512, 0.125f, 64, 8);
        SET(5,  W_out_w + 512 * 512,  512, W2to,               512, 1.f,    64, 8);
        SET(6,  W_in_w + 512 * 512,   512, W2ti,               512, 1.f,    64, 8);
        SET(7,  o_w,                  512, o_wT,               512, 1.f,    64, 8);
        SET(8,  v_w,                  512, v_wT,               512, 1.f,    64, 8);
        SET(9,  fc1_w,               2048, fc1T,               512, 1.f,   256, 32);
        SET(10, fc2_w,                512, fc2T,              2048, 1.f,   256, 8);
        k_prepAll<<<2058 + a.start[11], 256, 0, stream>>>(a);
    }

    // batched Q-side projections: QWcat = Qm @ [W1o|W3o|W1i|W3i|q*.125] + bias1
    {
        MMP m = {};
        m.A = Qm; m.lda = 512; m.Bt = WcatT; m.ldb = 512;
        m.bias = bias1; m.biasScale = 1.f;
        m.outF = QWcat; m.ldo = 2560; m.K = 512;
        k_mm<<<dim3(8, 40), 256, 0, stream>>>(m);
    }
    k_prep2<<<dim3(64, 2), 256, 0, stream>>>(QWcat + 2048, 2560, kwT, k_b, pbuf, cbuf);

    // both arcs in one dispatch
    k_midU<<<4096, 256, 0, stream>>>(arc_out, arc_in, W2to, W2ti, QWcat, Ubuf0, Ubuf1);
    k_att2<<<1024, 256, 0, stream>>>(Ubuf0, Ubuf1, pbuf, cbuf, Wsum0, Wsum1);

    // Linear post-attention, summed over arcs:
    // att_out+att_in = (bf16(Wsum0+Wsum1)@v_w per-head + 2*v_b)@o_w + 2*o_b
    {
        MMP m = {};
        m.Af2a = Wsum0; m.Af2b = Wsum1; m.ldaf = 4096; m.aOffPerN64 = 512;
        m.A = (const unsigned short*)Wsum0;  // unused (fused path)
        m.Bt = v_wT; m.ldb = 512;
        m.bias = v_b; m.biasScale = 2.f;
        m.outB = tmpb; m.ldo = 512; m.K = 512;
        k_mm<<<dim3(8, 8), 256, 0, stream>>>(m);
    }
    {
        MMP m = {};
        m.A = tmpb; m.lda = 512; m.Bt = o_wT; m.ldb = 512;
        m.bias = o_b; m.biasScale = 2.f;
        m.outF = attsum; m.ldo = 512; m.K = 512;
        k_mm<<<dim3(8, 8), 256, 0, stream>>>(m);
    }

    k_ln<<<512, 256, 0, stream>>>(h, attsum, 1, nullptr, nullptr, ln1_g, ln1_b, x1, x1b);

    {
        MMP m = {};
        m.A = x1b; m.lda = 512; m.Bt = fc1T; m.ldb = 512;
        m.bias = fc1_b; m.biasScale = 1.f;
        m.relu = 1; m.outB = ybb; m.ldo = 2048; m.K = 512;
        k_mm<<<dim3(8, 32), 256, 0, stream>>>(m);
    }
    {
        MMP m = {};
        m.A = ybb; m.lda = 2048; m.Bt = fc2T; m.ldb = 2048;
        m.outF = zparts; m.ldo = 512; m.K = 512;
        m.zKOff = 512; m.zOutOff = 262144;
        k_mm<<<dim3(8, 8, 4), 256, 0, stream>>>(m);
    }
    k_ln<<<512, 256, 0, stream>>>(x1, nullptr, 0, zparts, fc2_b, ln2_g, ln2_b, out, nullptr);
}

// Round 14
// 339.542 us; speedup vs baseline: 1.5639x; 1.0159x over previous
//
#include <hip/hip_runtime.h>
#include <stdint.h>
#include <stddef.h>

// Shapes: D=512, F=2048, H=8, L=128, B=4
#define NTOK 512      // B*L tokens
#define NM   65536    // B*L*L edge rows

typedef __bf16 bf16x8 __attribute__((ext_vector_type(8)));
typedef float  f32x4  __attribute__((ext_vector_type(4)));
typedef unsigned int u32x4 __attribute__((ext_vector_type(4)));

__device__ __forceinline__ unsigned short f2bf(float f) {
    unsigned int u = __builtin_bit_cast(unsigned int, f);
    u += 0x7FFFu + ((u >> 16) & 1u);
    return (unsigned short)(u >> 16);
}
__device__ __forceinline__ float bf2f(unsigned short s) {
    unsigned int u = ((unsigned int)s) << 16;
    return __builtin_bit_cast(float, u);
}

// async global->LDS, 16B per lane; LDS dest is wave-uniform base + lane*16
__device__ __forceinline__ void gload16(const void* g, void* l) {
    __builtin_amdgcn_global_load_lds(
        (const __attribute__((address_space(1))) void*)g,
        (__attribute__((address_space(3))) void*)l,
        16, 0, 0);
}

// ---------- merged prep + weight transposes (independent work, one launch) ----------
struct TRJob { const float* src; unsigned short* dst; int srcLd, dstLd, tcols; float scale; };
struct PrepArgs {
    const float* h; unsigned short* Qm;
    const float* kw; float* kwT;
    const float* Wob; const float* Wib; const float* qb; float* bias1;
    TRJob j[11]; int start[12];
};

__global__ __launch_bounds__(256) void k_prepAll(PrepArgs a) {
    __shared__ float tile[64][65];
    int bid = blockIdx.x;
    int t = threadIdx.x;
    if (bid < 1024) {                       // h (L,B,D) -> Qm bf16 (b*128+i, 512)
        int idx = bid * 256 + t;
        int tok = idx >> 9, d = idx & 511;
        int b = tok >> 7, i = tok & 127;
        a.Qm[idx] = f2bf(a.h[(i * 4 + b) * 512 + d]);
        return;
    } else if (bid < 2048) {                // kwT[e][d] = k_w[d][e]
        int idx = (bid - 1024) * 256 + t;
        a.kwT[idx] = a.kw[(size_t)(idx & 511) * 512 + (idx >> 9)];
        return;
    } else if (bid < 2058) {                // bias1 concat
        int i = (bid - 2048) * 256 + t;
        if (i < 2560) {
            float v = 0.f;
            if (i < 512) v = a.Wob[i];
            else if (i < 1024) v = 0.f;
            else if (i < 1536) v = a.Wib[i - 1024];
            else if (i < 2048) v = 0.f;
            else v = a.qb[i - 2048] * 0.125f;
            a.bias1[i] = v;
        }
        return;
    }
    // weight transpose tiles
    int b = bid - 2058;
    int ji = 0;
    while (ji < 10 && b >= a.start[ji + 1]) ++ji;
    TRJob jb = a.j[ji];
    int rel = b - a.start[ji];
    int bx = rel % jb.tcols, by = rel / jb.tcols;
    int r0 = by * 64, c0 = bx * 64;
    int c = t & 63, rr = t >> 6;
    #pragma unroll
    for (int ii = 0; ii < 16; ++ii) {
        int r = ii * 4 + rr;
        tile[r][c] = jb.src[(size_t)(r0 + r) * jb.srcLd + c0 + c];
    }
    __syncthreads();
    #pragma unroll
    for (int ii = 0; ii < 16; ++ii) {
        int n = ii * 4 + rr;
        jb.dst[(size_t)(c0 + n) * jb.dstLd + r0 + c] = f2bf(tile[c][n] * jb.scale);
    }
}

// ---------- generic bf16 MFMA GEMM: out = relu(A@B^T + bias*biasScale) [+accs] ----------
// Optional fused fp32-sum A path: A := bf16(Af2a + Af2b) staged on the fly.
struct MMP {
    const unsigned short* A;  int lda;
    const float* Af2a; const float* Af2b; int ldaf;
    const unsigned short* Bt; int ldb;
    const float* bias;
    const float* accs;
    float* outF;
    unsigned short* outB;
    int ldo;
    int K;
    int relu;
    int aOffPerN64;
    int zKOff;
    int zOutOff;
    float biasScale;
};

__global__ __launch_bounds__(256) void k_mm(MMP p) {
    __shared__ unsigned char As[64 * 128];
    __shared__ unsigned char Bs[64 * 128];
    int t = threadIdx.x;
    int lane = t & 63, w = t >> 6;
    int m0 = blockIdx.x * 64, n0 = blockIdx.y * 64;
    int z = blockIdx.z;
    size_t aoffel = (size_t)(n0 >> 6) * p.aOffPerN64 + (size_t)z * p.zKOff;
    const unsigned short* A  = p.A + aoffel;
    const unsigned short* Bt = p.Bt + (size_t)z * p.zKOff;
    int wm = (w >> 1) * 32, wn = (w & 1) * 32;
    f32x4 acc[2][2];
    #pragma unroll
    for (int a = 0; a < 2; ++a)
        #pragma unroll
        for (int b = 0; b < 2; ++b) acc[a][b] = (f32x4){0.f, 0.f, 0.f, 0.f};

    for (int kb = 0; kb < p.K; kb += 64) {
        __syncthreads();
        #pragma unroll
        for (int s = 0; s < 2; ++s) {
            int c = t + s * 256;
            int r = c >> 3, kc = (c & 7) * 8;
            int off = (r * 128 + kc * 2) ^ ((r & 7) << 4);
            if (p.Af2a) {
                size_t ro = aoffel + (size_t)(m0 + r) * p.ldaf + kb + kc;
                const float4* xa = reinterpret_cast<const float4*>(p.Af2a + ro);
                const float4* ya = reinterpret_cast<const float4*>(p.Af2b + ro);
                float4 x0 = xa[0], x1 = xa[1], y0 = ya[0], y1 = ya[1];
                bf16x8 bv;
                bv[0] = (__bf16)(x0.x + y0.x); bv[1] = (__bf16)(x0.y + y0.y);
                bv[2] = (__bf16)(x0.z + y0.z); bv[3] = (__bf16)(x0.w + y0.w);
                bv[4] = (__bf16)(x1.x + y1.x); bv[5] = (__bf16)(x1.y + y1.y);
                bv[6] = (__bf16)(x1.z + y1.z); bv[7] = (__bf16)(x1.w + y1.w);
                *reinterpret_cast<bf16x8*>(As + off) = bv;
            } else {
                *reinterpret_cast<u32x4*>(As + off) =
                    *reinterpret_cast<const u32x4*>(A + (size_t)(m0 + r) * p.lda + kb + kc);
            }
            *reinterpret_cast<u32x4*>(Bs + off) =
                *reinterpret_cast<const u32x4*>(Bt + (size_t)(n0 + r) * p.ldb + kb + kc);
        }
        __syncthreads();
        #pragma unroll
        for (int kh = 0; kh < 2; ++kh) {
            int kk = kh * 32 + (lane >> 4) * 8;
            bf16x8 af[2], bfr[2];
            #pragma unroll
            for (int mf = 0; mf < 2; ++mf) {
                int r = wm + mf * 16 + (lane & 15);
                int off = (r * 128 + kk * 2) ^ ((r & 7) << 4);
                af[mf] = *reinterpret_cast<const bf16x8*>(As + off);
            }
            #pragma unroll
            for (int nf = 0; nf < 2; ++nf) {
                int r = wn + nf * 16 + (lane & 15);
                int off = (r * 128 + kk * 2) ^ ((r & 7) << 4);
                bfr[nf] = *reinterpret_cast<const bf16x8*>(Bs + off);
            }
            #pragma unroll
            for (int mf = 0; mf < 2; ++mf)
                #pragma unroll
                for (int nf = 0; nf < 2; ++nf)
                    acc[mf][nf] = __builtin_amdgcn_mfma_f32_16x16x32_bf16(
                        af[mf], bfr[nf], acc[mf][nf], 0, 0, 0);
        }
    }
    #pragma unroll
    for (int mf = 0; mf < 2; ++mf) {
        #pragma unroll
        for (int rr = 0; rr < 4; ++rr) {
            int gm = m0 + wm + mf * 16 + (lane >> 4) * 4 + rr;
            #pragma unroll
            for (int nf = 0; nf < 2; ++nf) {
                int e = n0 + wn + nf * 16 + (lane & 15);
                float v = acc[mf][nf][rr];
                if (p.bias) v += p.bias[e] * p.biasScale;
                if (p.relu) v = fmaxf(v, 0.f);
                if (p.accs) v += p.accs[(size_t)gm * p.ldo + e];
                size_t oo = (size_t)gm * p.ldo + e + (size_t)z * p.zOutOff;
                if (p.outF) p.outF[oo] = v;
                if (p.outB) p.outB[oo] = f2bf(v);
            }
        }
    }
}

// ---------- p[tok][h][d] = sum_dh kwT[h*64+dh][d]*qs[tok][h*64+dh]; c[tok][h] ----------
__global__ __launch_bounds__(256) void k_prep2(const float* __restrict__ qs, int qld,
                                               const float* __restrict__ kwT,
                                               const float* __restrict__ k_b,
                                               unsigned short* __restrict__ p,
                                               float* __restrict__ c) {
    __shared__ float q8[8][512];
    int t = threadIdx.x;
    int tok0 = blockIdx.x * 8;
    int d = blockIdx.y * 256 + t;
    for (int idx = t; idx < 4096; idx += 256) {
        int s = idx >> 9, dd = idx & 511;
        q8[s][dd] = qs[(size_t)(tok0 + s) * qld + dd];
    }
    __syncthreads();
    if (blockIdx.y == 0 && t < 64) {
        int s = t >> 3, hh = t & 7;
        float cv = 0.f;
        for (int dh = 0; dh < 64; ++dh) cv += k_b[hh * 64 + dh] * q8[s][hh * 64 + dh];
        c[(tok0 + s) * 8 + hh] = cv;
    }
    for (int hh = 0; hh < 8; ++hh) {
        float pv[8];
        #pragma unroll
        for (int s = 0; s < 8; ++s) pv[s] = 0.f;
        for (int dh = 0; dh < 64; ++dh) {
            float wv = kwT[(size_t)(hh * 64 + dh) * 512 + d];
            #pragma unroll
            for (int s = 0; s < 8; ++s) pv[s] += wv * q8[s][hh * 64 + dh];
        }
        #pragma unroll
        for (int s = 0; s < 8; ++s)
            p[((size_t)(tok0 + s) * 8 + hh) * 512 + d] = f2bf(pv[s]);
    }
}

// ---------- edge MLP, BOTH arcs in one dispatch (4096 blocks) ----------
// R10 structure + K-PHASE STAGGER: co-resident blocks on a CU are the 4
// n-siblings of one m-slab (slot&3); without stagger they fetch/drain/compute
// in lockstep and latency never overlaps. Block nt starts its K loop at chunk
// (nt*2)&7 and wraps -> co-resident blocks sit at phases {0,2,4,6}: one
// drains while others compute. Accumulation order fixed per block (determ.).
__global__ __launch_bounds__(256) void k_midU(const float* __restrict__ arcO,
                                              const float* __restrict__ arcI,
                                              const unsigned short* __restrict__ W2to,
                                              const unsigned short* __restrict__ W2ti,
                                              const float* __restrict__ QWcat,
                                              unsigned short* __restrict__ U0,
                                              unsigned short* __restrict__ U1) {
    __shared__ float As4[128 * 64];            // 32KB fp32 A tile (swizzled storage)
    __shared__ unsigned short Bs2[128 * 64];   // 16KB bf16 B tile
    int t = threadIdx.x;
    int lane = t & 63;
    int w = t >> 6;
    int bid = blockIdx.x;
    int xcd = bid & 7, slot = bid >> 3;          // 512 slots per xcd
    int mtf = xcd * 128 + (slot >> 2);           // 0..1023 combined m-tile
    int nt = slot & 3;                           // 4 n-siblings adjacent on one XCD
    int arc01 = mtf >> 9;
    int mt = mtf & 511;
    const float* arc = arc01 ? arcI : arcO;
    const unsigned short* W2t = arc01 ? W2ti : W2to;
    const float* fixedMat = QWcat + (arc01 ? 1536 : 0);
    const float* rowMat   = QWcat + (arc01 ? 1024 : 512);
    unsigned short* U = arc01 ? U1 : U0;
    int m0 = mt * 128;
    int n0 = nt * 128;
    int wm = (w >> 1) * 64, wn = (w & 1) * 64;
    f32x4 acc[4][4];
    #pragma unroll
    for (int a = 0; a < 4; ++a)
        #pragma unroll
        for (int bq = 0; bq < 4; ++bq) acc[a][bq] = (f32x4){0.f, 0.f, 0.f, 0.f};

    int arA = lane >> 4;                 // A: row within 4-row group
    int acb = lane & 15;                 // A: 16B chunk within 256B row
    int brB = lane >> 3;                 // B: row within 8-row group
    int bcb = lane & 7;                  // B: 16B chunk within 128B row
    int ph0 = nt * 2;                    // K-phase stagger per n-sibling

    for (int s8 = 0; s8 < 8; ++s8) {
        int kb = (((s8 + ph0) & 7)) * 64;
        __syncthreads();
        #pragma unroll
        for (int i = 0; i < 8; ++i) {
            int base = (w * 8 + i) * 1024;
            int r = ((w * 8 + i) << 2) + arA;
            int cs = acb ^ (r & 7);
            gload16(arc + (size_t)(m0 + r) * 512 + kb + cs * 4,
                    (char*)As4 + base);
        }
        #pragma unroll
        for (int i = 0; i < 4; ++i) {
            int base = (w * 4 + i) * 1024;
            int r = ((w * 4 + i) << 3) + brB;
            int cs = bcb ^ (r & 7);
            gload16(W2t + (size_t)(n0 + r) * 512 + kb + cs * 8,
                    (char*)Bs2 + base);
        }
        __syncthreads();
        #pragma unroll
        for (int kh = 0; kh < 2; ++kh) {
            int kk = kh * 32 + (lane >> 4) * 8;
            bf16x8 af[4], bfr[4];
            #pragma unroll
            for (int mf = 0; mf < 4; ++mf) {
                int rr = wm + mf * 16 + (lane & 15);
                int c0 = kk >> 2;
                const char* bp = (const char*)As4 + rr * 256;
                float4 a0 = *reinterpret_cast<const float4*>(bp + ((c0 ^ (rr & 7)) << 4));
                float4 a1 = *reinterpret_cast<const float4*>(bp + (((c0 + 1) ^ (rr & 7)) << 4));
                af[mf][0] = (__bf16)a0.x; af[mf][1] = (__bf16)a0.y;
                af[mf][2] = (__bf16)a0.z; af[mf][3] = (__bf16)a0.w;
                af[mf][4] = (__bf16)a1.x; af[mf][5] = (__bf16)a1.y;
                af[mf][6] = (__bf16)a1.z; af[mf][7] = (__bf16)a1.w;
            }
            #pragma unroll
            for (int nf = 0; nf < 4; ++nf) {
                int rn = wn + nf * 16 + (lane & 15);
                int c = kk >> 3;
                bfr[nf] = *reinterpret_cast<const bf16x8*>(
                    (const char*)Bs2 + rn * 128 + ((c ^ (rn & 7)) << 4));
            }
            #pragma unroll
            for (int mf = 0; mf < 4; ++mf)
                #pragma unroll
                for (int nf = 0; nf < 4; ++nf)
                    acc[mf][nf] = __builtin_amdgcn_mfma_f32_16x16x32_bf16(
                        af[mf], bfr[nf], acc[mf][nf], 0, 0, 0);
        }
    }
    int tokI = mt;
    int bb = mt >> 7;
    float fx[4];
    #pragma unroll
    for (int nf = 0; nf < 4; ++nf)
        fx[nf] = fixedMat[(size_t)tokI * 2560 + n0 + wn + nf * 16 + (lane & 15)];
    #pragma unroll
    for (int mf = 0; mf < 4; ++mf) {
        #pragma unroll
        for (int r = 0; r < 4; ++r) {
            int row = wm + mf * 16 + (lane >> 4) * 4 + r;
            int gm = m0 + row;
            int tokJ = bb * 128 + (gm & 127);
            const float* rv = rowMat + (size_t)tokJ * 2560;
            #pragma unroll
            for (int nf = 0; nf < 4; ++nf) {
                int e = n0 + wn + nf * 16 + (lane & 15);
                float v = acc[mf][nf][r] + fx[nf] + rv[e];
                v = fmaxf(v, 0.f);
                U[(size_t)gm * 512 + e] = f2bf(v);
            }
        }
    }
}

// ---------- fused scores+softmax+wacc, BOTH arcs (1024 blocks) ----------
__global__ __launch_bounds__(256) void k_att2(const unsigned short* __restrict__ U0,
                                              const unsigned short* __restrict__ U1,
                                              const unsigned short* __restrict__ p,
                                              const float* __restrict__ c,
                                              float* __restrict__ Wsum0,
                                              float* __restrict__ Wsum1) {
    __shared__ float at[8][128];
    int bid = blockIdx.x;
    int arc01 = bid >> 9;
    int tok = bid & 511;
    const unsigned short* U = arc01 ? U1 : U0;
    float* Ws = arc01 ? Wsum1 : Wsum0;
    int t = threadIdx.x;
    int w = t >> 6;
    int lane = t & 63;
    int hh = lane & 15;
    int kg = lane >> 4;
    bool hv = hh < 8;
    f32x4 acc[2];
    acc[0] = (f32x4){0.f, 0.f, 0.f, 0.f};
    acc[1] = (f32x4){0.f, 0.f, 0.f, 0.f};
    const unsigned short* Ub0 = U + (size_t)tok * 65536;
    const unsigned short* Ub = Ub0 + (size_t)(w * 32) * 512;
    const unsigned short* pb = p + ((size_t)tok * 8 + (hh & 7)) * 512;
    for (int ks = 0; ks < 16; ++ks) {
        int kcol = ks * 32 + kg * 8;
        u32x4 braw = (u32x4){0u, 0u, 0u, 0u};
        if (hv) braw = *reinterpret_cast<const u32x4*>(pb + kcol);
        bf16x8 bfrag = __builtin_bit_cast(bf16x8, braw);
        #pragma unroll
        for (int mf = 0; mf < 2; ++mf) {
            bf16x8 afrag = *reinterpret_cast<const bf16x8*>(
                Ub + (size_t)(mf * 16 + hh) * 512 + kcol);
            acc[mf] = __builtin_amdgcn_mfma_f32_16x16x32_bf16(afrag, bfrag, acc[mf], 0, 0, 0);
        }
    }
    if (hv) {
        float cval = c[tok * 8 + hh];
        #pragma unroll
        for (int mf = 0; mf < 2; ++mf)
            #pragma unroll
            for (int r = 0; r < 4; ++r)
                at[hh][w * 32 + mf * 16 + kg * 4 + r] = acc[mf][r] + cval;
    }
    __syncthreads();
    {
        int h2 = t >> 5, l32 = t & 31;
        float v0 = at[h2][l32], v1 = at[h2][l32 + 32],
              v2 = at[h2][l32 + 64], v3 = at[h2][l32 + 96];
        float mx = fmaxf(fmaxf(v0, v1), fmaxf(v2, v3));
        #pragma unroll
        for (int o = 16; o >= 1; o >>= 1) mx = fmaxf(mx, __shfl_xor(mx, o));
        float e0 = __expf(v0 - mx), e1 = __expf(v1 - mx),
              e2 = __expf(v2 - mx), e3 = __expf(v3 - mx);
        float sum = e0 + e1 + e2 + e3;
        #pragma unroll
        for (int o = 16; o >= 1; o >>= 1) sum += __shfl_xor(sum, o);
        float inv = 1.f / sum;
        at[h2][l32]      = e0 * inv;
        at[h2][l32 + 32] = e1 * inv;
        at[h2][l32 + 64] = e2 * inv;
        at[h2][l32 + 96] = e3 * inv;
    }
    __syncthreads();
    int d0 = t * 2;
    float a8[8][2];
    #pragma unroll
    for (int q = 0; q < 8; ++q) { a8[q][0] = 0.f; a8[q][1] = 0.f; }
    for (int j = 0; j < 128; ++j) {
        unsigned int uv = *reinterpret_cast<const unsigned int*>(Ub0 + (size_t)j * 512 + d0);
        float u0 = bf2f((unsigned short)(uv & 0xffffu));
        float u1 = bf2f((unsigned short)(uv >> 16));
        #pragma unroll
        for (int q = 0; q < 8; ++q) {
            float a = at[q][j];
            a8[q][0] += a * u0;
            a8[q][1] += a * u1;
        }
    }
    #pragma unroll
    for (int q = 0; q < 8; ++q) {
        size_t woff = ((size_t)tok * 8 + q) * 512 + d0;
        Ws[woff] = a8[q][0];
        Ws[woff + 1] = a8[q][1];
    }
}

// ---------- layernorm: out = LN(A + B) * g + beta ----------
__global__ __launch_bounds__(256) void k_ln(const float* __restrict__ A,
                                            const float* __restrict__ Bv, int bswap,
                                            const float* __restrict__ parts,
                                            const float* __restrict__ pbias,
                                            const float* __restrict__ g,
                                            const float* __restrict__ bta,
                                            float* __restrict__ outF,
                                            unsigned short* __restrict__ outB) {
    int t = threadIdx.x;
    int tok = blockIdx.x;
    size_t aoff = (size_t)tok * 512;
    float b0, b1;
    if (parts) {
        b0 = parts[aoff + t] + parts[262144 + aoff + t] +
             parts[524288 + aoff + t] + parts[786432 + aoff + t] + pbias[t];
        b1 = parts[aoff + t + 256] + parts[262144 + aoff + t + 256] +
             parts[524288 + aoff + t + 256] + parts[786432 + aoff + t + 256] + pbias[t + 256];
    } else {
        size_t boff = aoff;
        if (bswap) { int i = tok >> 2, b = tok & 3; boff = (size_t)(b * 128 + i) * 512; }
        b0 = Bv[boff + t];
        b1 = Bv[boff + t + 256];
    }
    float v0 = A[aoff + t] + b0;
    float v1 = A[aoff + t + 256] + b1;
    float s = v0 + v1, q = v0 * v0 + v1 * v1;
    #pragma unroll
    for (int o = 32; o >= 1; o >>= 1) { s += __shfl_xor(s, o); q += __shfl_xor(q, o); }
    __shared__ float red[8];
    int w = t >> 6, lane = t & 63;
    if (lane == 0) { red[w] = s; red[4 + w] = q; }
    __syncthreads();
    float ts = red[0] + red[1] + red[2] + red[3];
    float tq = red[4] + red[5] + red[6] + red[7];
    float mean = ts * (1.f / 512.f);
    float var = tq * (1.f / 512.f) - mean * mean;
    float inv = rsqrtf(var + 1e-5f);
    float o0 = (v0 - mean) * inv * g[t] + bta[t];
    float o1 = (v1 - mean) * inv * g[t + 256] + bta[t + 256];
    outF[aoff + t] = o0;
    outF[aoff + t + 256] = o1;
    if (outB) { outB[aoff + t] = f2bf(o0); outB[aoff + t + 256] = f2bf(o1); }
}

extern "C" void kernel_launch(void* const* d_in, const int* in_sizes, int n_in,
                              void* d_out, int out_size, void* d_ws, size_t ws_size,
                              hipStream_t stream) {
    (void)in_sizes; (void)n_in; (void)out_size; (void)ws_size;
    const float* h       = (const float*)d_in[0];
    const float* arc_out = (const float*)d_in[1];
    const float* arc_in  = (const float*)d_in[2];
    const float* W_out_w = (const float*)d_in[4];
    const float* W_out_b = (const float*)d_in[5];
    const float* W_in_w  = (const float*)d_in[6];
    const float* W_in_b  = (const float*)d_in[7];
    const float* q_w  = (const float*)d_in[8];
    const float* q_b  = (const float*)d_in[9];
    const float* k_w  = (const float*)d_in[10];
    const float* k_b  = (const float*)d_in[11];
    const float* v_w  = (const float*)d_in[12];
    const float* v_b  = (const float*)d_in[13];
    const float* o_w  = (const float*)d_in[14];
    const float* o_b  = (const float*)d_in[15];
    const float* ln1_g = (const float*)d_in[16];
    const float* ln1_b = (const float*)d_in[17];
    const float* fc1_w = (const float*)d_in[18];
    const float* fc1_b = (const float*)d_in[19];
    const float* fc2_w = (const float*)d_in[20];
    const float* fc2_b = (const float*)d_in[21];
    const float* ln2_g = (const float*)d_in[22];
    const float* ln2_b = (const float*)d_in[23];
    float* out = (float*)d_out;

    char* wsb = (char*)d_ws;
    size_t off = 0;
    auto ALLOC = [&](size_t bytes) -> void* {
        void* ptr = wsb + off;
        off += (bytes + 255) & ~(size_t)255;
        return ptr;
    };
    unsigned short* WcatT = (unsigned short*)ALLOC((size_t)2560 * 512 * 2);
    unsigned short* W2to  = (unsigned short*)ALLOC(262144 * 2);
    unsigned short* W2ti  = (unsigned short*)ALLOC(262144 * 2);
    unsigned short* o_wT  = (unsigned short*)ALLOC(262144 * 2);
    unsigned short* v_wT  = (unsigned short*)ALLOC(262144 * 2);
    unsigned short* fc1T  = (unsigned short*)ALLOC((size_t)2048 * 512 * 2);
    unsigned short* fc2T  = (unsigned short*)ALLOC((size_t)512 * 2048 * 2);
    float* kwT   = (float*)ALLOC(262144 * 4);
    float* bias1 = (float*)ALLOC(2560 * 4);
    unsigned short* Qm = (unsigned short*)ALLOC(262144 * 2);
    float* QWcat = (float*)ALLOC((size_t)512 * 2560 * 4);
    unsigned short* pbuf = (unsigned short*)ALLOC((size_t)NTOK * 8 * 512 * 2);
    float* cbuf = (float*)ALLOC(NTOK * 8 * 4);
    unsigned short* Ubuf0 = (unsigned short*)ALLOC((size_t)NM * 512 * 2);
    unsigned short* Ubuf1 = (unsigned short*)ALLOC((size_t)NM * 512 * 2);
    float* Wsum0 = (float*)ALLOC((size_t)NTOK * 8 * 512 * 4);
    float* Wsum1 = (float*)ALLOC((size_t)NTOK * 8 * 512 * 4);
    unsigned short* tmpb  = (unsigned short*)ALLOC(262144 * 2);
    float* attsum = (float*)ALLOC(262144 * 4);
    float* x1  = (float*)ALLOC(262144 * 4);
    unsigned short* x1b = (unsigned short*)ALLOC(262144 * 2);
    unsigned short* ybb = (unsigned short*)ALLOC((size_t)NTOK * 2048 * 2);
    float* zparts = (float*)ALLOC((size_t)4 * 262144 * 4);

    // merged prep + transposes (single launch)
    {
        PrepArgs a = {};
        a.h = h; a.Qm = Qm; a.kw = k_w; a.kwT = kwT;
        a.Wob = W_out_b; a.Wib = W_in_b; a.qb = q_b; a.bias1 = bias1;
        auto SET = [&](int i, const float* s, int sld, unsigned short* d, int dld,
                       float sc, int tiles, int tcols) {
            a.j[i] = TRJob{s, d, sld, dld, tcols, sc};
            a.start[i + 1] = a.start[i] + tiles;
        };
        a.start[0] = 0;
        SET(0,  W_out_w,              512, WcatT,              512, 1.f,    64, 8);
        SET(1,  W_out_w + 1024 * 512, 512, WcatT + 512 * 512,  512, 1.f,    64, 8);
        SET(2,  W_in_w,               512, WcatT + 1024 * 512, 512, 1.f,    64, 8);
        SET(3,  W_in_w + 1024 * 512,  512, WcatT + 1536 * 512, 512, 1.f,    64, 8);
        SET(4,  q_w,                  512, WcatT + 2048 * 512, 512, 0.125f, 64, 8);
        SET(5,  W_out_w + 512 * 512,  512, W2to,               512, 1.f,    64, 8);
        SET(6,  W_in_w + 512 * 512,   512, W2ti,               512, 1.f,    64, 8);
        SET(7,  o_w,                  512, o_wT,               512, 1.f,    64, 8);
        SET(8,  v_w,                  512, v_wT,               512, 1.f,    64, 8);
        SET(9,  fc1_w,               2048, fc1T,               512, 1.f,   256, 32);
        SET(10, fc2_w,                512, fc2T,              2048, 1.f,   256, 8);
        k_prepAll<<<2058 + a.start[11], 256, 0, stream>>>(a);
    }

    // batched Q-side projections: QWcat = Qm @ [W1o|W3o|W1i|W3i|q*.125] + bias1
    {
        MMP m = {};
        m.A = Qm; m.lda = 512; m.Bt = WcatT; m.ldb = 512;
        m.bias = bias1; m.biasScale = 1.f;
        m.outF = QWcat; m.ldo = 2560; m.K = 512;
        k_mm<<<dim3(8, 40), 256, 0, stream>>>(m);
    }
    k_prep2<<<dim3(64, 2), 256, 0, stream>>>(QWcat + 2048, 2560, kwT, k_b, pbuf, cbuf);

    // both arcs in one dispatch
    k_midU<<<4096, 256, 0, stream>>>(arc_out, arc_in, W2to, W2ti, QWcat, Ubuf0, Ubuf1);
    k_att2<<<1024, 256, 0, stream>>>(Ubuf0, Ubuf1, pbuf, cbuf, Wsum0, Wsum1);

    // Linear post-attention, summed over arcs:
    // att_out+att_in = (bf16(Wsum0+Wsum1)@v_w per-head + 2*v_b)@o_w + 2*o_b
    {
        MMP m = {};
        m.Af2a = Wsum0; m.Af2b = Wsum1; m.ldaf = 4096; m.aOffPerN64 = 512;
        m.A = (const unsigned short*)Wsum0;  // unused (fused path)
        m.Bt = v_wT; m.ldb = 512;
        m.bias = v_b; m.biasScale = 2.f;
        m.outB = tmpb; m.ldo = 512; m.K = 512;
        k_mm<<<dim3(8, 8), 256, 0, stream>>>(m);
    }
    {
        MMP m = {};
        m.A = tmpb; m.lda = 512; m.Bt = o_wT; m.ldb = 512;
        m.bias = o_b; m.biasScale = 2.f;
        m.outF = attsum; m.ldo = 512; m.K = 512;
        k_mm<<<dim3(8, 8), 256, 0, stream>>>(m);
    }

    k_ln<<<512, 256, 0, stream>>>(h, attsum, 1, nullptr, nullptr, ln1_g, ln1_b, x1, x1b);

    {
        MMP m = {};
        m.A = x1b; m.lda = 512; m.Bt = fc1T; m.ldb = 512;
        m.bias = fc1_b; m.biasScale = 1.f;
        m.relu = 1; m.outB = ybb; m.ldo = 2048; m.K = 512;
        k_mm<<<dim3(8, 32), 256, 0, stream>>>(m);
    }
    {
        MMP m = {};
        m.A = ybb; m.lda = 2048; m.Bt = fc2T; m.ldb = 2048;
        m.outF = zparts; m.ldo = 512; m.K = 512;
        m.zKOff = 512; m.zOutOff = 262144;
        k_mm<<<dim3(8, 8, 4), 256, 0, stream>>>(m);
    }
    k_ln<<<512, 256, 0, stream>>>(x1, nullptr, 0, zparts, fc2_b, ln2_g, ln2_b, out, nullptr);
}